// Round 3
// baseline (632.850 us; speedup 1.0000x reference)
//
#include <hip/hip_runtime.h>
#include <cstdint>
#include <cstddef>

typedef __bf16 bf16;
typedef __bf16 bf16x8 __attribute__((ext_vector_type(8)));
typedef __bf16 bf16x4 __attribute__((ext_vector_type(4)));
typedef float f32x4 __attribute__((ext_vector_type(4)));

#define DEVI __device__ __forceinline__

DEVI void gload_lds16(const bf16* g, bf16* l) {
    __builtin_amdgcn_global_load_lds(
        (const __attribute__((address_space(1))) void*)(const void*)g,
        (__attribute__((address_space(3))) void*)(void*)l, 16, 0, 0);
}

// ---------------- weight convert + transpose: W[K][N] f32 -> Wt[N][K] bf16 ----
__global__ void conv_t_kernel(const float* __restrict__ W, bf16* __restrict__ Wt,
                              int K, int N) {
    __shared__ float tile[64][65];
    const int tid = threadIdx.x;
    const int c  = tid & 63;
    const int r4 = tid >> 6;   // 0..3
    const int n0 = blockIdx.x * 64;
    const int k0 = blockIdx.y * 64;
#pragma unroll
    for (int r = 0; r < 64; r += 4)
        tile[r + r4][c] = W[(size_t)(k0 + r + r4) * N + n0 + c];
    __syncthreads();
#pragma unroll
    for (int r = 0; r < 64; r += 4)
        Wt[(size_t)(n0 + r + r4) * K + k0 + c] = (bf16)tile[c][r + r4];
}

// ---------------- DyT: h = gamma*tanh(alpha*x)+beta  (f32 -> bf16) -----------
__global__ void dyt_kernel(const float* __restrict__ x, const float* __restrict__ alpha,
                           const float* __restrict__ gamma, const float* __restrict__ beta,
                           bf16* __restrict__ h, int total) {
    int i4 = (blockIdx.x * 256 + threadIdx.x) * 4;
    if (i4 >= total) return;
    float a = alpha[0];
    float4 xv = *(const float4*)&x[i4];
    int c = i4 & 1023;
    float4 g  = *(const float4*)&gamma[c];
    float4 bt = *(const float4*)&beta[c];
    bf16x4 o;
    o[0] = (bf16)(g.x * tanhf(xv.x * a) + bt.x);
    o[1] = (bf16)(g.y * tanhf(xv.y * a) + bt.y);
    o[2] = (bf16)(g.z * tanhf(xv.z * a) + bt.z);
    o[3] = (bf16)(g.w * tanhf(xv.w * a) + bt.w);
    *(bf16x4*)&h[i4] = o;
}

// ---------------- GEMM: C = A[M][K] @ Wt[N][K]^T, 128x128x32, 4 waves --------
template<int OP>
__global__ void gemm_kernel(const bf16* __restrict__ A, const bf16* __restrict__ Wt,
                            const float* __restrict__ bias, const float* resid,
                            float* outf, bf16* outb,
                            const float* __restrict__ alpha_p,
                            const float* __restrict__ gamma,
                            const float* __restrict__ beta,
                            int M, int N, int K) {
    __shared__ bf16 As[128 * 32];
    __shared__ bf16 Bs[128 * 32];
    const int tid  = threadIdx.x;
    const int lane = tid & 63;
    const int w    = tid >> 6;
    const int wr   = w >> 1, wc = w & 1;

    // bijective XCD swizzle (nwg divisible by 8 for all our grids)
    const int nwgx = gridDim.x;
    const int nwg  = gridDim.x * gridDim.y;
    const int orig = blockIdx.y * nwgx + blockIdx.x;
    const int cpx  = nwg >> 3;
    const int swz  = (orig & 7) * cpx + (orig >> 3);
    const int bm = (swz / nwgx) * 128;
    const int bn = (swz % nwgx) * 128;

    f32x4 acc[4][4] = {};

    const bf16* a0 = A  + (size_t)(bm + (tid >> 2)) * K + (tid & 3) * 8;
    const bf16* a1 = a0 + (size_t)64 * K;
    const bf16* b0 = Wt + (size_t)(bn + (tid >> 2)) * K + (tid & 3) * 8;
    const bf16* b1 = b0 + (size_t)64 * K;
    bf16* lA0 = As + tid * 8;
    bf16* lA1 = As + 2048 + tid * 8;
    bf16* lB0 = Bs + tid * 8;
    bf16* lB1 = Bs + 2048 + tid * 8;

    const int arow = wr * 64 + (lane & 15);
    const int brow = wc * 64 + (lane & 15);
    const int koff = (lane >> 4) * 8;

    for (int k0 = 0; k0 < K; k0 += 32) {
        __syncthreads();
        gload_lds16(a0, lA0);
        gload_lds16(a1, lA1);
        gload_lds16(b0, lB0);
        gload_lds16(b1, lB1);
        a0 += 32; a1 += 32; b0 += 32; b1 += 32;
        __syncthreads();
        bf16x8 af[4], bfr[4];
#pragma unroll
        for (int i = 0; i < 4; i++)
            af[i] = *(const bf16x8*)&As[(arow + i * 16) * 32 + koff];
#pragma unroll
        for (int i = 0; i < 4; i++)
            bfr[i] = *(const bf16x8*)&Bs[(brow + i * 16) * 32 + koff];
#pragma unroll
        for (int i = 0; i < 4; i++)
#pragma unroll
            for (int j = 0; j < 4; j++)
                acc[i][j] = __builtin_amdgcn_mfma_f32_16x16x32_bf16(af[i], bfr[j], acc[i][j], 0, 0, 0);
    }

    const int lh = lane >> 4, lm = lane & 15;
#pragma unroll
    for (int i = 0; i < 4; i++) {
        const int row0 = bm + wr * 64 + i * 16 + lh * 4;
#pragma unroll
        for (int jf = 0; jf < 4; jf++) {
            const int col = bn + wc * 64 + jf * 16 + lm;
            const float bval = bias[col];
#pragma unroll
            for (int r = 0; r < 4; r++) {
                const int row = row0 + r;
                const size_t idx = (size_t)row * N + col;
                float v = acc[i][jf][r] + bval;
                if (OP == 0) {
                    outb[idx] = (bf16)v;
                } else if (OP == 1) {
                    v += resid[idx];
                    outf[idx] = v;
                    float hh = gamma[col] * tanhf(v * alpha_p[0]) + beta[col];
                    outb[idx] = (bf16)hh;
                } else if (OP == 2) {
                    float g = 0.5f * v * (1.0f + erff(v * 0.70710678118f));
                    outb[idx] = (bf16)g;
                } else {
                    v += resid[idx];
                    outf[idx] = v;
                }
            }
        }
    }
}

// ---------------- causal flash attention, H=16 D=64 T=2048 -------------------
// Balanced: block j handles q-tiles (j, 31-j) -> every block = 33 MFMA tiles.
// Both q-tiles share staged V and K fragments. K reg-double-buffered (prefetch
// next tile), V staging split load-early/write-late. Swapped QK^T: lane owns
// one q-row, softmax = in-lane + 2 shfl_xor.
__global__ void attn_kernel(const bf16* __restrict__ qkv, bf16* __restrict__ out) {
    const int j  = blockIdx.x;          // pair index 0..15
    const int bh = blockIdx.y;          // b*16 + h
    const int b = bh >> 4, h = bh & 15;
    const int tid = threadIdx.x, lane = tid & 63, w = tid >> 6;
    const int T = 2048;
    const size_t C3 = 3072;
    const bf16* qb = qkv + (size_t)b * T * C3 + h * 64;
    const bf16* kb = qb + 1024;
    const bf16* vb = qb + 2048;

    __shared__ bf16 Vt[2][64][72];      // [buf][d][k-swizzled]
    __shared__ bf16 Pl[4][2][16][72];   // [wave][slot A/B][q][k]

    const int tA = j, tB = 31 - j;
    const int qA = tA * 64 + w * 16;
    const int qB = tB * 64 + w * 16;
    const int lm = lane & 15, lh = lane >> 4;

    bf16x8 qfA0, qfA1, qfB0, qfB1;
    {
        size_t qo = (size_t)(qA + lm) * C3 + lh * 8;
        qfA0 = *(const bf16x8*)&qb[qo];
        qfA1 = *(const bf16x8*)&qb[qo + 32];
        qo = (size_t)(qB + lm) * C3 + lh * 8;
        qfB0 = *(const bf16x8*)&qb[qo];
        qfB1 = *(const bf16x8*)&qb[qo + 32];
    }
    f32x4 accA[4] = {}, accB[4] = {};
    float mstA = -1e30f, sumA = 0.f, mstB = -1e30f, sumB = 0.f;

    const int sg = tid & 7;             // d-group (8 rows of Vt)
    const int sq = tid >> 3;            // k-quad (tid<128)
    bf16x8 rv[4];

    auto loadV = [&](int k0) {
        if (tid < 128) {
#pragma unroll
            for (int i = 0; i < 4; ++i)
                rv[i] = *(const bf16x8*)&vb[(size_t)(k0 + sq * 4 + i) * C3 + sg * 8];
        }
    };
    auto writeV = [&](int buf) {
        if (tid < 128) {
            const int cbase = ((((sq >> 1) ^ sg) & 7) << 3) + ((sq & 1) << 2);
#pragma unroll
            for (int e = 0; e < 8; ++e) {
                bf16x4 wv;
                wv[0] = rv[0][e]; wv[1] = rv[1][e]; wv[2] = rv[2][e]; wv[3] = rv[3][e];
                *(bf16x4*)&Vt[buf][sg * 8 + e][cbase] = wv;
            }
        }
    };
    auto loadK = [&](bf16x8 (&kf)[4][2], int k0) {
#pragma unroll
        for (int f = 0; f < 4; ++f) {
            size_t kg = (size_t)(k0 + f * 16 + lm) * C3 + lh * 8;
            kf[f][0] = *(const bf16x8*)&kb[kg];
            kf[f][1] = *(const bf16x8*)&kb[kg + 32];
        }
    };

    // softmax + PV for one q-tile
    auto process = [&](f32x4 (&s)[4], f32x4 (&acc)[4], float& mst, float& sum,
                       int slot, int buf) {
        float m0 = fmaxf(fmaxf(s[0][0], s[0][1]), fmaxf(s[0][2], s[0][3]));
        float m1 = fmaxf(fmaxf(s[1][0], s[1][1]), fmaxf(s[1][2], s[1][3]));
        float m2 = fmaxf(fmaxf(s[2][0], s[2][1]), fmaxf(s[2][2], s[2][3]));
        float m3 = fmaxf(fmaxf(s[3][0], s[3][1]), fmaxf(s[3][2], s[3][3]));
        float pm = fmaxf(fmaxf(m0, m1), fmaxf(m2, m3));
        pm = fmaxf(pm, __shfl_xor(pm, 16));
        pm = fmaxf(pm, __shfl_xor(pm, 32));
        const float mnew = fmaxf(mst, pm);
        const float corr = __expf(mst - mnew);
        mst = mnew;
        float rs = 0.f;
#pragma unroll
        for (int f = 0; f < 4; ++f) {
            bf16x4 pw;
#pragma unroll
            for (int r = 0; r < 4; ++r) {
                const float pv = __expf(s[f][r] - mnew);
                rs += pv;
                pw[r] = (bf16)pv;
            }
            *(bf16x4*)&Pl[w][slot][lm][f * 16 + lh * 4] = pw;
        }
        rs += __shfl_xor(rs, 16);
        rs += __shfl_xor(rs, 32);
        sum = sum * corr + rs;
        float cq[4];
#pragma unroll
        for (int r = 0; r < 4; ++r) cq[r] = __shfl(corr, lh * 4 + r);
#pragma unroll
        for (int df = 0; df < 4; ++df)
#pragma unroll
            for (int r = 0; r < 4; ++r) acc[df][r] *= cq[r];
#pragma unroll
        for (int kk = 0; kk < 2; ++kk) {
            bf16x8 pa = *(const bf16x8*)&Pl[w][slot][lm][kk * 32 + lh * 8];
            const int kblk = 4 * kk + lh;
#pragma unroll
            for (int df = 0; df < 4; ++df) {
                const int dr = df * 16 + lm;
                bf16x8 vf = *(const bf16x8*)&Vt[buf][dr][((kblk ^ ((dr >> 3) & 7)) << 3)];
                acc[df] = __builtin_amdgcn_mfma_f32_16x16x32_bf16(pa, vf, acc[df], 0, 0, 0);
            }
        }
    };

    auto qkT = [&](f32x4 (&s)[4], bf16x8 (&kf)[4][2], bf16x8& q0, bf16x8& q1) {
#pragma unroll
        for (int f = 0; f < 4; ++f) {
            f32x4 z = {};
            z = __builtin_amdgcn_mfma_f32_16x16x32_bf16(kf[f][0], q0, z, 0, 0, 0);
            z = __builtin_amdgcn_mfma_f32_16x16x32_bf16(kf[f][1], q1, z, 0, 0, 0);
            s[f] = z;
        }
    };
    auto maskscale = [&](f32x4 (&s)[4], int k0, int qg, bool diag) {
        if (diag) {
#pragma unroll
            for (int f = 0; f < 4; ++f)
#pragma unroll
                for (int r = 0; r < 4; ++r) {
                    const int kgl = k0 + f * 16 + lh * 4 + r;
                    float v = s[f][r] * 0.125f;
                    s[f][r] = (kgl > qg) ? -1e30f : v;
                }
        } else {
#pragma unroll
            for (int f = 0; f < 4; ++f)
#pragma unroll
                for (int r = 0; r < 4; ++r) s[f][r] *= 0.125f;
        }
    };

    bf16x8 kf0[4][2], kf1[4][2];

    // one KV-tile body; kcur holds K frags for tile kt, knext gets tile kt+1
    auto body = [&](int kt, bf16x8 (&kcur)[4][2], bf16x8 (&knext)[4][2]) {
        const int k0 = kt * 64;
        const int buf = kt & 1;
        const bool hasNext = kt < tB;
        if (hasNext) {
            loadK(knext, k0 + 64);
            loadV(k0 + 64);
        }
        f32x4 sB[4];
        qkT(sB, kcur, qfB0, qfB1);
        maskscale(sB, k0, qB + lm, kt == tB);
        const bool actA = (kt <= tA);
        if (actA) {
            f32x4 sA[4];
            qkT(sA, kcur, qfA0, qfA1);
            maskscale(sA, k0, qA + lm, kt == tA);
            process(sA, accA, mstA, sumA, 0, buf);
        }
        if (hasNext) writeV(buf ^ 1);
        process(sB, accB, mstB, sumB, 1, buf);
        __syncthreads();
    };

    loadK(kf0, 0);
    loadV(0);
    writeV(0);
    __syncthreads();

    for (int kt = 0; kt <= tB; ++kt) {
        if (kt & 1) body(kt, kf1, kf0);
        else        body(kt, kf0, kf1);
    }

    // epilogue: write both q-tiles
    bf16* ob = out + (size_t)b * T * 1024 + h * 64;
    {
        const float linv = 1.0f / sumA;
        float iq[4];
#pragma unroll
        for (int r = 0; r < 4; ++r) iq[r] = __shfl(linv, lh * 4 + r);
#pragma unroll
        for (int r = 0; r < 4; ++r) {
            const int q = qA + lh * 4 + r;
#pragma unroll
            for (int df = 0; df < 4; ++df)
                ob[(size_t)q * 1024 + df * 16 + lm] = (bf16)(accA[df][r] * iq[r]);
        }
    }
    {
        const float linv = 1.0f / sumB;
        float iq[4];
#pragma unroll
        for (int r = 0; r < 4; ++r) iq[r] = __shfl(linv, lh * 4 + r);
#pragma unroll
        for (int r = 0; r < 4; ++r) {
            const int q = qB + lh * 4 + r;
#pragma unroll
            for (int df = 0; df < 4; ++df)
                ob[(size_t)q * 1024 + df * 16 + lm] = (bf16)(accB[df][r] * iq[r]);
        }
    }
}

// -----------------------------------------------------------------------------
extern "C" void kernel_launch(void* const* d_in, const int* in_sizes, int n_in,
                              void* d_out, int out_size, void* d_ws, size_t ws_size,
                              hipStream_t stream) {
    const float* x      = (const float*)d_in[0];
    const float* alpha  = (const float*)d_in[1];
    const float* gamma  = (const float*)d_in[2];
    const float* beta   = (const float*)d_in[3];
    const float* w_attn = (const float*)d_in[4];
    const float* b_attn = (const float*)d_in[5];
    const float* w_proj = (const float*)d_in[6];
    const float* b_proj = (const float*)d_in[7];
    const float* w_fc   = (const float*)d_in[8];
    const float* b_fc   = (const float*)d_in[9];
    const float* w_fc2  = (const float*)d_in[10];
    const float* b_fc2  = (const float*)d_in[11];
    float* out = (float*)d_out;

    const int M = 4096, C = 1024, F = 4096;
    char* ws = (char*)d_ws;
    bf16* wt_attn = (bf16*)ws;                        // [3C][C]   6 MB
    bf16* wt_proj = wt_attn + (size_t)3 * C * C;      // [C][C]    2 MB
    bf16* wt_fc   = wt_proj + (size_t)C * C;          // [F][C]    8 MB
    bf16* wt_fc2  = wt_fc   + (size_t)F * C;          // [C][F]    8 MB
    bf16* hbuf    = wt_fc2  + (size_t)C * F;          // [M][C]    8 MB (h, then h2)
    bf16* qkvbuf  = hbuf    + (size_t)M * C;          // [M][3C] then act [M][F] 32 MB
    bf16* aout    = qkvbuf  + (size_t)M * F;          // [M][C]    8 MB
    float* x2     = (float*)(aout + (size_t)M * C);   // [M][C]   16 MB

    dim3 blk(256);
    conv_t_kernel<<<dim3(3 * C / 64, C / 64), blk, 0, stream>>>(w_attn, wt_attn, C, 3 * C);
    conv_t_kernel<<<dim3(C / 64, C / 64),     blk, 0, stream>>>(w_proj, wt_proj, C, C);
    conv_t_kernel<<<dim3(F / 64, C / 64),     blk, 0, stream>>>(w_fc,   wt_fc,   C, F);
    conv_t_kernel<<<dim3(C / 64, F / 64),     blk, 0, stream>>>(w_fc2,  wt_fc2,  F, C);

    dyt_kernel<<<dim3(M * C / 1024), blk, 0, stream>>>(x, alpha, gamma, beta, hbuf, M * C);

    // QKV: [M][3C] = h @ w_attn
    gemm_kernel<0><<<dim3(3 * C / 128, M / 128), blk, 0, stream>>>(
        hbuf, wt_attn, b_attn, nullptr, nullptr, qkvbuf, nullptr, nullptr, nullptr, M, 3 * C, C);

    attn_kernel<<<dim3(16, 32), blk, 0, stream>>>(qkvbuf, aout);

    // proj + residual(x) -> x2 (f32) and h2 = DyT(x2) (bf16, into hbuf)
    gemm_kernel<1><<<dim3(C / 128, M / 128), blk, 0, stream>>>(
        aout, wt_proj, b_proj, x, x2, hbuf, alpha, gamma, beta, M, C, C);

    // fc + gelu -> act (reuse qkvbuf region, [M][F])
    gemm_kernel<2><<<dim3(F / 128, M / 128), blk, 0, stream>>>(
        hbuf, wt_fc, b_fc, nullptr, nullptr, qkvbuf, nullptr, nullptr, nullptr, M, F, C);

    // fc2 + residual(x2) -> d_out (f32)
    gemm_kernel<3><<<dim3(C / 128, M / 128), blk, 0, stream>>>(
        qkvbuf, wt_fc2, b_fc2, x2, out, nullptr, nullptr, nullptr, nullptr, M, C, F);
}

// Round 4
// 311.605 us; speedup vs baseline: 2.0309x; 2.0309x over previous
//
#include <hip/hip_runtime.h>
#include <cstdint>
#include <cstddef>

typedef __bf16 bf16;
typedef __bf16 bf16x8 __attribute__((ext_vector_type(8)));
typedef __bf16 bf16x4 __attribute__((ext_vector_type(4)));
typedef float f32x4 __attribute__((ext_vector_type(4)));

#define DEVI __device__ __forceinline__

DEVI void gload_lds16(const bf16* g, bf16* l) {
    __builtin_amdgcn_global_load_lds(
        (const __attribute__((address_space(1))) void*)(const void*)g,
        (__attribute__((address_space(3))) void*)(void*)l, 16, 0, 0);
}

// ---------------- weight convert + transpose: W[K][N] f32 -> Wt[N][K] bf16 ----
__global__ void conv_t_kernel(const float* __restrict__ W, bf16* __restrict__ Wt,
                              int K, int N) {
    __shared__ float tile[64][65];
    const int tid = threadIdx.x;
    const int c  = tid & 63;
    const int r4 = tid >> 6;   // 0..3
    const int n0 = blockIdx.x * 64;
    const int k0 = blockIdx.y * 64;
#pragma unroll
    for (int r = 0; r < 64; r += 4)
        tile[r + r4][c] = W[(size_t)(k0 + r + r4) * N + n0 + c];
    __syncthreads();
#pragma unroll
    for (int r = 0; r < 64; r += 4)
        Wt[(size_t)(n0 + r + r4) * K + k0 + c] = (bf16)tile[c][r + r4];
}

// ---------------- DyT: h = gamma*tanh(alpha*x)+beta  (f32 -> bf16) -----------
__global__ void dyt_kernel(const float* __restrict__ x, const float* __restrict__ alpha,
                           const float* __restrict__ gamma, const float* __restrict__ beta,
                           bf16* __restrict__ h, int total) {
    int i4 = (blockIdx.x * 256 + threadIdx.x) * 4;
    if (i4 >= total) return;
    float a = alpha[0];
    float4 xv = *(const float4*)&x[i4];
    int c = i4 & 1023;
    float4 g  = *(const float4*)&gamma[c];
    float4 bt = *(const float4*)&beta[c];
    bf16x4 o;
    o[0] = (bf16)(g.x * tanhf(xv.x * a) + bt.x);
    o[1] = (bf16)(g.y * tanhf(xv.y * a) + bt.y);
    o[2] = (bf16)(g.z * tanhf(xv.z * a) + bt.z);
    o[3] = (bf16)(g.w * tanhf(xv.w * a) + bt.w);
    *(bf16x4*)&h[i4] = o;
}

// ---------------- GEMM: C = A[M][K] @ Wt[N][K]^T, 128x128x32, 4 waves --------
template<int OP>
__global__ void gemm_kernel(const bf16* __restrict__ A, const bf16* __restrict__ Wt,
                            const float* __restrict__ bias, const float* resid,
                            float* outf, bf16* outb,
                            const float* __restrict__ alpha_p,
                            const float* __restrict__ gamma,
                            const float* __restrict__ beta,
                            int M, int N, int K) {
    __shared__ bf16 As[128 * 32];
    __shared__ bf16 Bs[128 * 32];
    const int tid  = threadIdx.x;
    const int lane = tid & 63;
    const int w    = tid >> 6;
    const int wr   = w >> 1, wc = w & 1;

    // bijective XCD swizzle (nwg divisible by 8 for all our grids)
    const int nwgx = gridDim.x;
    const int nwg  = gridDim.x * gridDim.y;
    const int orig = blockIdx.y * nwgx + blockIdx.x;
    const int cpx  = nwg >> 3;
    const int swz  = (orig & 7) * cpx + (orig >> 3);
    const int bm = (swz / nwgx) * 128;
    const int bn = (swz % nwgx) * 128;

    f32x4 acc[4][4] = {};

    const bf16* a0 = A  + (size_t)(bm + (tid >> 2)) * K + (tid & 3) * 8;
    const bf16* a1 = a0 + (size_t)64 * K;
    const bf16* b0 = Wt + (size_t)(bn + (tid >> 2)) * K + (tid & 3) * 8;
    const bf16* b1 = b0 + (size_t)64 * K;
    bf16* lA0 = As + tid * 8;
    bf16* lA1 = As + 2048 + tid * 8;
    bf16* lB0 = Bs + tid * 8;
    bf16* lB1 = Bs + 2048 + tid * 8;

    const int arow = wr * 64 + (lane & 15);
    const int brow = wc * 64 + (lane & 15);
    const int koff = (lane >> 4) * 8;

    for (int k0 = 0; k0 < K; k0 += 32) {
        __syncthreads();
        gload_lds16(a0, lA0);
        gload_lds16(a1, lA1);
        gload_lds16(b0, lB0);
        gload_lds16(b1, lB1);
        a0 += 32; a1 += 32; b0 += 32; b1 += 32;
        __syncthreads();
        bf16x8 af[4], bfr[4];
#pragma unroll
        for (int i = 0; i < 4; i++)
            af[i] = *(const bf16x8*)&As[(arow + i * 16) * 32 + koff];
#pragma unroll
        for (int i = 0; i < 4; i++)
            bfr[i] = *(const bf16x8*)&Bs[(brow + i * 16) * 32 + koff];
#pragma unroll
        for (int i = 0; i < 4; i++)
#pragma unroll
            for (int j = 0; j < 4; j++)
                acc[i][j] = __builtin_amdgcn_mfma_f32_16x16x32_bf16(af[i], bfr[j], acc[i][j], 0, 0, 0);
    }

    const int lh = lane >> 4, lm = lane & 15;
#pragma unroll
    for (int i = 0; i < 4; i++) {
        const int row0 = bm + wr * 64 + i * 16 + lh * 4;
#pragma unroll
        for (int jf = 0; jf < 4; jf++) {
            const int col = bn + wc * 64 + jf * 16 + lm;
            const float bval = bias[col];
#pragma unroll
            for (int r = 0; r < 4; r++) {
                const int row = row0 + r;
                const size_t idx = (size_t)row * N + col;
                float v = acc[i][jf][r] + bval;
                if (OP == 0) {
                    outb[idx] = (bf16)v;
                } else if (OP == 1) {
                    v += resid[idx];
                    outf[idx] = v;
                    float hh = gamma[col] * tanhf(v * alpha_p[0]) + beta[col];
                    outb[idx] = (bf16)hh;
                } else if (OP == 2) {
                    float g = 0.5f * v * (1.0f + erff(v * 0.70710678118f));
                    outb[idx] = (bf16)g;
                } else {
                    v += resid[idx];
                    outf[idx] = v;
                }
            }
        }
    }
}

// ---------------- causal flash attention, H=16 D=64 T=2048 -------------------
// Round-1 structure + (a) LPT order (heavy q-tiles dispatched first) and
// (b) K staged into LDS via double-buffered global_load_lds with
// inverse-swizzled global source + swizzled ds_read_b128 (conflict-free).
// Swapped QK^T: lane owns one q-row; softmax = in-lane + 2 shfl_xor.
__global__ void attn_kernel(const bf16* __restrict__ qkv, bf16* __restrict__ out) {
    const int bq = (gridDim.x - 1) - blockIdx.x;   // heavy tiles first (LPT)
    const int bh = blockIdx.y;                     // b*16 + h
    const int b = bh >> 4, h = bh & 15;
    const int tid = threadIdx.x, lane = tid & 63, w = tid >> 6;
    const int T = 2048;
    const size_t C3 = 3072;
    const bf16* qb = qkv + (size_t)b * T * C3 + h * 64;
    const bf16* kb = qb + 1024;
    const bf16* vb = qb + 2048;

    __shared__ bf16 Ks[2][64][64];      // [buf][kv][d], d-blocks XOR-swizzled by kv&7
    __shared__ bf16 Vt[2][64][72];      // [buf][d][k-swizzled]
    __shared__ bf16 Pl[4][16][72];      // per-wave P [q][k]

    const int q0w = bq * 64 + w * 16;
    const int lm = lane & 15;
    const int lh = lane >> 4;

    bf16x8 qf0, qf1;
    {
        size_t qoff = (size_t)(q0w + lm) * C3 + lh * 8;
        qf0 = *(const bf16x8*)&qb[qoff];
        qf1 = *(const bf16x8*)&qb[qoff + 32];
    }
    f32x4 acc[4] = {};                  // O[q=lh*4+r][d=df*16+lm]
    float mS = -1e30f, lS = 0.f;        // stats for q = q0w+lm (replicated x4)

    const int nt = bq + 1;
    const int sg = tid & 7;             // d-group (8 rows of Vt)
    const int sq = tid >> 3;            // k-quad, valid 0..15 for tid<128
    bf16x8 rv[4];

    // K staging: thread tid covers rows (tid>>3) and (tid>>3)+32, 16B block tid&7.
    // Global source block is (cb ^ (row&7)) so LDS ends up holding
    // Ks[row][(blk ^ (row&7))*8 .. +7] = K[row][blk*8 .. +7].
    const int krow = tid >> 3;
    const int kcb  = tid & 7;
    const int kcbs = (kcb ^ (krow & 7)) * 8;
    auto stageK = [&](int buf, int k0) {
        gload_lds16(&kb[(size_t)(k0 + krow) * C3 + kcbs],      &Ks[buf][0][0]  + tid * 8);
        gload_lds16(&kb[(size_t)(k0 + 32 + krow) * C3 + kcbs], &Ks[buf][32][0] + tid * 8);
    };
    auto loadV = [&](int k0) {
        if (tid < 128) {
#pragma unroll
            for (int i = 0; i < 4; ++i)
                rv[i] = *(const bf16x8*)&vb[(size_t)(k0 + sq * 4 + i) * C3 + sg * 8];
        }
    };
    auto writeV = [&](int buf) {
        if (tid < 128) {
            const int cbase = ((((sq >> 1) ^ sg) & 7) << 3) + ((sq & 1) << 2);
#pragma unroll
            for (int e = 0; e < 8; ++e) {
                bf16x4 wv;
                wv[0] = rv[0][e]; wv[1] = rv[1][e]; wv[2] = rv[2][e]; wv[3] = rv[3][e];
                *(bf16x4*)&Vt[buf][sg * 8 + e][cbase] = wv;
            }
        }
    };

    stageK(0, 0);
    loadV(0);
    writeV(0);
    __syncthreads();

    for (int kt = 0; kt < nt; ++kt) {
        const int k0 = kt * 64;
        const int buf = kt & 1;
        if (kt + 1 < nt) {
            stageK(buf ^ 1, k0 + 64);
            loadV(k0 + 64);
        }

        // S^T fragments from LDS K: s[f][r] = S[k0+f*16+lh*4+r][q0w+lm]
        f32x4 s[4];
#pragma unroll
        for (int f = 0; f < 4; ++f) {
            const int row = f * 16 + lm;
            const int sw = (row & 7);
            bf16x8 kf0v = *(const bf16x8*)&Ks[buf][row][(lh ^ sw) * 8];
            bf16x8 kf1v = *(const bf16x8*)&Ks[buf][row][((lh + 4) ^ sw) * 8];
            f32x4 z = {};
            z = __builtin_amdgcn_mfma_f32_16x16x32_bf16(kf0v, qf0, z, 0, 0, 0);
            z = __builtin_amdgcn_mfma_f32_16x16x32_bf16(kf1v, qf1, z, 0, 0, 0);
            s[f] = z;
        }
        const int qg = q0w + lm;
        if (kt == bq) {
#pragma unroll
            for (int f = 0; f < 4; ++f)
#pragma unroll
                for (int r = 0; r < 4; ++r) {
                    const int kgl = k0 + f * 16 + lh * 4 + r;
                    float v = s[f][r] * 0.125f;
                    s[f][r] = (kgl > qg) ? -1e30f : v;
                }
        } else {
#pragma unroll
            for (int f = 0; f < 4; ++f)
#pragma unroll
                for (int r = 0; r < 4; ++r) s[f][r] *= 0.125f;
        }

        // online softmax for row q = qg (in-lane + 2 shfl)
        float m0 = fmaxf(fmaxf(s[0][0], s[0][1]), fmaxf(s[0][2], s[0][3]));
        float m1 = fmaxf(fmaxf(s[1][0], s[1][1]), fmaxf(s[1][2], s[1][3]));
        float m2 = fmaxf(fmaxf(s[2][0], s[2][1]), fmaxf(s[2][2], s[2][3]));
        float m3 = fmaxf(fmaxf(s[3][0], s[3][1]), fmaxf(s[3][2], s[3][3]));
        float pm = fmaxf(fmaxf(m0, m1), fmaxf(m2, m3));
        pm = fmaxf(pm, __shfl_xor(pm, 16));
        pm = fmaxf(pm, __shfl_xor(pm, 32));
        const float mnew = fmaxf(mS, pm);
        const float corr = __expf(mS - mnew);
        mS = mnew;

        float rs = 0.f;
#pragma unroll
        for (int f = 0; f < 4; ++f) {
            bf16x4 pw;
#pragma unroll
            for (int r = 0; r < 4; ++r) {
                const float pv = __expf(s[f][r] - mnew);
                rs += pv;
                pw[r] = (bf16)pv;
            }
            *(bf16x4*)&Pl[w][lm][f * 16 + lh * 4] = pw;
        }
        rs += __shfl_xor(rs, 16);
        rs += __shfl_xor(rs, 32);
        lS = lS * corr + rs;

        if (kt + 1 < nt) writeV(buf ^ 1);

        // redistribute corr to acc layout (q = lh*4+r)
        float cq[4];
#pragma unroll
        for (int r = 0; r < 4; ++r) cq[r] = __shfl(corr, lh * 4 + r);
#pragma unroll
        for (int df = 0; df < 4; ++df)
#pragma unroll
            for (int r = 0; r < 4; ++r) acc[df][r] *= cq[r];

        // PV: O += P @ V
#pragma unroll
        for (int kk = 0; kk < 2; ++kk) {
            bf16x8 pa = *(const bf16x8*)&Pl[w][lm][kk * 32 + lh * 8];
            const int kblk = 4 * kk + lh;
#pragma unroll
            for (int df = 0; df < 4; ++df) {
                const int dr = df * 16 + lm;
                bf16x8 vf = *(const bf16x8*)&Vt[buf][dr][((kblk ^ ((dr >> 3) & 7)) << 3)];
                acc[df] = __builtin_amdgcn_mfma_f32_16x16x32_bf16(pa, vf, acc[df], 0, 0, 0);
            }
        }
        __syncthreads();
    }

    // epilogue
    const float linv = 1.0f / lS;
    float iq[4];
#pragma unroll
    for (int r = 0; r < 4; ++r) iq[r] = __shfl(linv, lh * 4 + r);
    bf16* ob = out + (size_t)b * T * 1024 + h * 64;
#pragma unroll
    for (int r = 0; r < 4; ++r) {
        const int q = q0w + lh * 4 + r;
#pragma unroll
        for (int df = 0; df < 4; ++df)
            ob[(size_t)q * 1024 + df * 16 + lm] = (bf16)(acc[df][r] * iq[r]);
    }
}

// -----------------------------------------------------------------------------
extern "C" void kernel_launch(void* const* d_in, const int* in_sizes, int n_in,
                              void* d_out, int out_size, void* d_ws, size_t ws_size,
                              hipStream_t stream) {
    const float* x      = (const float*)d_in[0];
    const float* alpha  = (const float*)d_in[1];
    const float* gamma  = (const float*)d_in[2];
    const float* beta   = (const float*)d_in[3];
    const float* w_attn = (const float*)d_in[4];
    const float* b_attn = (const float*)d_in[5];
    const float* w_proj = (const float*)d_in[6];
    const float* b_proj = (const float*)d_in[7];
    const float* w_fc   = (const float*)d_in[8];
    const float* b_fc   = (const float*)d_in[9];
    const float* w_fc2  = (const float*)d_in[10];
    const float* b_fc2  = (const float*)d_in[11];
    float* out = (float*)d_out;

    const int M = 4096, C = 1024, F = 4096;
    char* ws = (char*)d_ws;
    bf16* wt_attn = (bf16*)ws;                        // [3C][C]   6 MB
    bf16* wt_proj = wt_attn + (size_t)3 * C * C;      // [C][C]    2 MB
    bf16* wt_fc   = wt_proj + (size_t)C * C;          // [F][C]    8 MB
    bf16* wt_fc2  = wt_fc   + (size_t)F * C;          // [C][F]    8 MB
    bf16* hbuf    = wt_fc2  + (size_t)C * F;          // [M][C]    8 MB (h, then h2)
    bf16* qkvbuf  = hbuf    + (size_t)M * C;          // [M][3C] then act [M][F] 32 MB
    bf16* aout    = qkvbuf  + (size_t)M * F;          // [M][C]    8 MB
    float* x2     = (float*)(aout + (size_t)M * C);   // [M][C]   16 MB

    dim3 blk(256);
    conv_t_kernel<<<dim3(3 * C / 64, C / 64), blk, 0, stream>>>(w_attn, wt_attn, C, 3 * C);
    conv_t_kernel<<<dim3(C / 64, C / 64),     blk, 0, stream>>>(w_proj, wt_proj, C, C);
    conv_t_kernel<<<dim3(F / 64, C / 64),     blk, 0, stream>>>(w_fc,   wt_fc,   C, F);
    conv_t_kernel<<<dim3(C / 64, F / 64),     blk, 0, stream>>>(w_fc2,  wt_fc2,  F, C);

    dyt_kernel<<<dim3(M * C / 1024), blk, 0, stream>>>(x, alpha, gamma, beta, hbuf, M * C);

    // QKV: [M][3C] = h @ w_attn
    gemm_kernel<0><<<dim3(3 * C / 128, M / 128), blk, 0, stream>>>(
        hbuf, wt_attn, b_attn, nullptr, nullptr, qkvbuf, nullptr, nullptr, nullptr, M, 3 * C, C);

    attn_kernel<<<dim3(32, 32), blk, 0, stream>>>(qkvbuf, aout);

    // proj + residual(x) -> x2 (f32) and h2 = DyT(x2) (bf16, into hbuf)
    gemm_kernel<1><<<dim3(C / 128, M / 128), blk, 0, stream>>>(
        aout, wt_proj, b_proj, x, x2, hbuf, alpha, gamma, beta, M, C, C);

    // fc + gelu -> act (reuse qkvbuf region, [M][F])
    gemm_kernel<2><<<dim3(F / 128, M / 128), blk, 0, stream>>>(
        hbuf, wt_fc, b_fc, nullptr, nullptr, qkvbuf, nullptr, nullptr, nullptr, M, F, C);

    // fc2 + residual(x2) -> d_out (f32)
    gemm_kernel<3><<<dim3(C / 128, M / 128), blk, 0, stream>>>(
        qkvbuf, wt_fc2, b_fc2, x2, out, nullptr, nullptr, nullptr, nullptr, M, C, F);
}

// Round 5
// 283.874 us; speedup vs baseline: 2.2293x; 1.0977x over previous
//
#include <hip/hip_runtime.h>
#include <cstdint>
#include <cstddef>

typedef __bf16 bf16;
typedef __bf16 bf16x8 __attribute__((ext_vector_type(8)));
typedef __bf16 bf16x4 __attribute__((ext_vector_type(4)));
typedef float f32x4 __attribute__((ext_vector_type(4)));

#define DEVI __device__ __forceinline__

DEVI void gload_lds16(const bf16* g, bf16* l) {
    __builtin_amdgcn_global_load_lds(
        (const __attribute__((address_space(1))) void*)(const void*)g,
        (__attribute__((address_space(3))) void*)(void*)l, 16, 0, 0);
}

// ---------------- weight convert + transpose: W[K][N] f32 -> Wt[N][K] bf16 ----
__global__ void conv_t_kernel(const float* __restrict__ W, bf16* __restrict__ Wt,
                              int K, int N) {
    __shared__ float tile[64][65];
    const int tid = threadIdx.x;
    const int c  = tid & 63;
    const int r4 = tid >> 6;   // 0..3
    const int n0 = blockIdx.x * 64;
    const int k0 = blockIdx.y * 64;
#pragma unroll
    for (int r = 0; r < 64; r += 4)
        tile[r + r4][c] = W[(size_t)(k0 + r + r4) * N + n0 + c];
    __syncthreads();
#pragma unroll
    for (int r = 0; r < 64; r += 4)
        Wt[(size_t)(n0 + r + r4) * K + k0 + c] = (bf16)tile[c][r + r4];
}

// ---------------- DyT: h = gamma*tanh(alpha*x)+beta  (f32 -> bf16) -----------
__global__ void dyt_kernel(const float* __restrict__ x, const float* __restrict__ alpha,
                           const float* __restrict__ gamma, const float* __restrict__ beta,
                           bf16* __restrict__ h, int total) {
    int i4 = (blockIdx.x * 256 + threadIdx.x) * 4;
    if (i4 >= total) return;
    float a = alpha[0];
    float4 xv = *(const float4*)&x[i4];
    int c = i4 & 1023;
    float4 g  = *(const float4*)&gamma[c];
    float4 bt = *(const float4*)&beta[c];
    bf16x4 o;
    o[0] = (bf16)(g.x * tanhf(xv.x * a) + bt.x);
    o[1] = (bf16)(g.y * tanhf(xv.y * a) + bt.y);
    o[2] = (bf16)(g.z * tanhf(xv.z * a) + bt.z);
    o[3] = (bf16)(g.w * tanhf(xv.w * a) + bt.w);
    *(bf16x4*)&h[i4] = o;
}

// ---------------- reduce for split-K fc2: out = p0 + p1 + bias + resid -------
__global__ void reduce2_kernel(const float* __restrict__ p, const float* __restrict__ bias,
                               const float* __restrict__ resid, float* __restrict__ out,
                               int total) {
    int i4 = (blockIdx.x * 256 + threadIdx.x) * 4;
    if (i4 >= total) return;
    float4 a = *(const float4*)&p[i4];
    float4 bsec = *(const float4*)&p[(size_t)total + i4];
    float4 r = *(const float4*)&resid[i4];
    int c = i4 & 1023;
    float4 bb = *(const float4*)&bias[c];
    float4 o;
    o.x = a.x + bsec.x + r.x + bb.x;
    o.y = a.y + bsec.y + r.y + bb.y;
    o.z = a.z + bsec.z + r.z + bb.z;
    o.w = a.w + bsec.w + r.w + bb.w;
    *(float4*)&out[i4] = o;
}

// ---------------- GEMM: C = A[M][lda] @ Wt[N][ldb]^T, 128x128x32, 4 waves ----
// 2-phase prefetch: stage tile t+1 (global_load_lds, dbuf LDS) before compute
// of tile t; single barrier per K-step. LDS group-swizzled (g ^= (row>>1)&3)
// on both stage-source and ds_read -> conflict-free b128 reads.
// OP 0: out_bf16 = acc + bias                         (QKV)
// OP 1: v = acc+bias+resid; out_f32 = v; out_bf16 = DyT(v)
// OP 2: out_bf16 = gelu_exact(acc + bias)             (fc)
// OP 3: out_f32 = acc + bias + resid                  (fc2 full-K)
// OP 4: out_f32[z*M*N + idx] = acc                    (fc2 split-K partial)
template<int OP>
__global__ void gemm_kernel(const bf16* __restrict__ A, const bf16* __restrict__ Wt,
                            const float* __restrict__ bias, const float* resid,
                            float* outf, bf16* outb,
                            const float* __restrict__ alpha_p,
                            const float* __restrict__ gamma,
                            const float* __restrict__ beta,
                            int M, int N, int K, int lda, int ldb) {
    __shared__ bf16 As[2][128 * 32];
    __shared__ bf16 Bs[2][128 * 32];
    const int tid  = threadIdx.x;
    const int lane = tid & 63;
    const int w    = tid >> 6;
    const int wr   = w >> 1, wc = w & 1;

    // bijective XCD swizzle (nwg divisible by 8 for all our grids)
    const int nwgx = gridDim.x;
    const int nwg  = gridDim.x * gridDim.y;
    const int orig = blockIdx.y * nwgx + blockIdx.x;
    const int cpx  = nwg >> 3;
    const int swz  = (orig & 7) * cpx + (orig >> 3);
    const int bm = (swz / nwgx) * 128;
    const int bn = (swz % nwgx) * 128;
    const int kz = blockIdx.z * K;          // split-K offset

    f32x4 acc[4][4] = {};

    // staging: thread covers rows srow, srow+64; 16B group (tid&3), source
    // group inverse-swizzled so LDS[row][gp] = glob[row][gp ^ ((row>>1)&3)]
    const int srow = tid >> 2;
    const int sgrp = ((tid & 3) ^ ((srow >> 1) & 3)) * 8;
    const bf16* a0 = A  + (size_t)(bm + srow) * lda + kz + sgrp;
    const bf16* a1 = a0 + (size_t)64 * lda;
    const bf16* b0 = Wt + (size_t)(bn + srow) * ldb + kz + sgrp;
    const bf16* b1 = b0 + (size_t)64 * ldb;

    auto stage = [&](int buf) {
        gload_lds16(a0, &As[buf][tid * 8]);
        gload_lds16(a1, &As[buf][2048 + tid * 8]);
        gload_lds16(b0, &Bs[buf][tid * 8]);
        gload_lds16(b1, &Bs[buf][2048 + tid * 8]);
        a0 += 32; a1 += 32; b0 += 32; b1 += 32;
    };

    const int lh = lane >> 4, lm = lane & 15;
    const int arow = wr * 64 + lm;
    const int brow = wc * 64 + lm;
    const int gsw = (lh ^ ((lm >> 1) & 3)) * 8;   // swizzled group offset

    stage(0);
    __syncthreads();

    const int nk = K >> 5;
    for (int kt = 0; kt < nk; ++kt) {
        const int cur = kt & 1;
        if (kt + 1 < nk) stage(cur ^ 1);
        bf16x8 af[4], bfr[4];
#pragma unroll
        for (int i = 0; i < 4; i++)
            af[i] = *(const bf16x8*)&As[cur][(arow + i * 16) * 32 + gsw];
#pragma unroll
        for (int i = 0; i < 4; i++)
            bfr[i] = *(const bf16x8*)&Bs[cur][(brow + i * 16) * 32 + gsw];
#pragma unroll
        for (int i = 0; i < 4; i++)
#pragma unroll
            for (int j = 0; j < 4; j++)
                acc[i][j] = __builtin_amdgcn_mfma_f32_16x16x32_bf16(af[i], bfr[j], acc[i][j], 0, 0, 0);
        __syncthreads();
    }

#pragma unroll
    for (int i = 0; i < 4; i++) {
        const int row0 = bm + wr * 64 + i * 16 + lh * 4;
#pragma unroll
        for (int jf = 0; jf < 4; jf++) {
            const int col = bn + wc * 64 + jf * 16 + lm;
            const float bval = (OP == 4) ? 0.f : bias[col];
#pragma unroll
            for (int r = 0; r < 4; r++) {
                const int row = row0 + r;
                const size_t idx = (size_t)row * N + col;
                float v = acc[i][jf][r] + bval;
                if (OP == 0) {
                    outb[idx] = (bf16)v;
                } else if (OP == 1) {
                    v += resid[idx];
                    outf[idx] = v;
                    float hh = gamma[col] * tanhf(v * alpha_p[0]) + beta[col];
                    outb[idx] = (bf16)hh;
                } else if (OP == 2) {
                    float g = 0.5f * v * (1.0f + erff(v * 0.70710678118f));
                    outb[idx] = (bf16)g;
                } else if (OP == 3) {
                    v += resid[idx];
                    outf[idx] = v;
                } else {
                    outf[(size_t)blockIdx.z * M * N + idx] = v;
                }
            }
        }
    }
}

// ---------------- causal flash attention, H=16 D=64 T=2048 -------------------
// LPT order (heavy q-tiles first); K staged via double-buffered global_load_lds
// (inverse-swizzled source + swizzled ds_read_b128); V reg-staged transposed.
// Swapped QK^T: lane owns one q-row; softmax = in-lane + 2 shfl_xor.
__global__ void attn_kernel(const bf16* __restrict__ qkv, bf16* __restrict__ out) {
    const int bq = (gridDim.x - 1) - blockIdx.x;   // heavy tiles first (LPT)
    const int bh = blockIdx.y;                     // b*16 + h
    const int b = bh >> 4, h = bh & 15;
    const int tid = threadIdx.x, lane = tid & 63, w = tid >> 6;
    const int T = 2048;
    const size_t C3 = 3072;
    const bf16* qb = qkv + (size_t)b * T * C3 + h * 64;
    const bf16* kb = qb + 1024;
    const bf16* vb = qb + 2048;

    __shared__ bf16 Ks[2][64][64];      // [buf][kv][d], d-blocks XOR-swizzled by kv&7
    __shared__ bf16 Vt[2][64][72];      // [buf][d][k-swizzled]
    __shared__ bf16 Pl[4][16][72];      // per-wave P [q][k]

    const int q0w = bq * 64 + w * 16;
    const int lm = lane & 15;
    const int lh = lane >> 4;

    bf16x8 qf0, qf1;
    {
        size_t qoff = (size_t)(q0w + lm) * C3 + lh * 8;
        qf0 = *(const bf16x8*)&qb[qoff];
        qf1 = *(const bf16x8*)&qb[qoff + 32];
    }
    f32x4 acc[4] = {};                  // O[q=lh*4+r][d=df*16+lm]
    float mS = -1e30f, lS = 0.f;        // stats for q = q0w+lm (replicated x4)

    const int nt = bq + 1;
    const int sg = tid & 7;             // d-group (8 rows of Vt)
    const int sq = tid >> 3;            // k-quad, valid 0..15 for tid<128
    bf16x8 rv[4];

    const int krow = tid >> 3;
    const int kcb  = tid & 7;
    const int kcbs = (kcb ^ (krow & 7)) * 8;
    auto stageK = [&](int buf, int k0) {
        gload_lds16(&kb[(size_t)(k0 + krow) * C3 + kcbs],      &Ks[buf][0][0]  + tid * 8);
        gload_lds16(&kb[(size_t)(k0 + 32 + krow) * C3 + kcbs], &Ks[buf][32][0] + tid * 8);
    };
    auto loadV = [&](int k0) {
        if (tid < 128) {
#pragma unroll
            for (int i = 0; i < 4; ++i)
                rv[i] = *(const bf16x8*)&vb[(size_t)(k0 + sq * 4 + i) * C3 + sg * 8];
        }
    };
    auto writeV = [&](int buf) {
        if (tid < 128) {
            const int cbase = ((((sq >> 1) ^ sg) & 7) << 3) + ((sq & 1) << 2);
#pragma unroll
            for (int e = 0; e < 8; ++e) {
                bf16x4 wv;
                wv[0] = rv[0][e]; wv[1] = rv[1][e]; wv[2] = rv[2][e]; wv[3] = rv[3][e];
                *(bf16x4*)&Vt[buf][sg * 8 + e][cbase] = wv;
            }
        }
    };

    stageK(0, 0);
    loadV(0);
    writeV(0);
    __syncthreads();

    for (int kt = 0; kt < nt; ++kt) {
        const int k0 = kt * 64;
        const int buf = kt & 1;
        if (kt + 1 < nt) {
            stageK(buf ^ 1, k0 + 64);
            loadV(k0 + 64);
        }

        // S^T fragments from LDS K: s[f][r] = S[k0+f*16+lh*4+r][q0w+lm]
        f32x4 s[4];
#pragma unroll
        for (int f = 0; f < 4; ++f) {
            const int row = f * 16 + lm;
            const int sw = (row & 7);
            bf16x8 kf0v = *(const bf16x8*)&Ks[buf][row][(lh ^ sw) * 8];
            bf16x8 kf1v = *(const bf16x8*)&Ks[buf][row][((lh + 4) ^ sw) * 8];
            f32x4 z = {};
            z = __builtin_amdgcn_mfma_f32_16x16x32_bf16(kf0v, qf0, z, 0, 0, 0);
            z = __builtin_amdgcn_mfma_f32_16x16x32_bf16(kf1v, qf1, z, 0, 0, 0);
            s[f] = z;
        }
        const int qg = q0w + lm;
        if (kt == bq) {
#pragma unroll
            for (int f = 0; f < 4; ++f)
#pragma unroll
                for (int r = 0; r < 4; ++r) {
                    const int kgl = k0 + f * 16 + lh * 4 + r;
                    float v = s[f][r] * 0.125f;
                    s[f][r] = (kgl > qg) ? -1e30f : v;
                }
        } else {
#pragma unroll
            for (int f = 0; f < 4; ++f)
#pragma unroll
                for (int r = 0; r < 4; ++r) s[f][r] *= 0.125f;
        }

        // online softmax for row q = qg (in-lane + 2 shfl)
        float m0 = fmaxf(fmaxf(s[0][0], s[0][1]), fmaxf(s[0][2], s[0][3]));
        float m1 = fmaxf(fmaxf(s[1][0], s[1][1]), fmaxf(s[1][2], s[1][3]));
        float m2 = fmaxf(fmaxf(s[2][0], s[2][1]), fmaxf(s[2][2], s[2][3]));
        float m3 = fmaxf(fmaxf(s[3][0], s[3][1]), fmaxf(s[3][2], s[3][3]));
        float pm = fmaxf(fmaxf(m0, m1), fmaxf(m2, m3));
        pm = fmaxf(pm, __shfl_xor(pm, 16));
        pm = fmaxf(pm, __shfl_xor(pm, 32));
        const float mnew = fmaxf(mS, pm);
        const float corr = __expf(mS - mnew);
        mS = mnew;

        float rs = 0.f;
#pragma unroll
        for (int f = 0; f < 4; ++f) {
            bf16x4 pw;
#pragma unroll
            for (int r = 0; r < 4; ++r) {
                const float pv = __expf(s[f][r] - mnew);
                rs += pv;
                pw[r] = (bf16)pv;
            }
            *(bf16x4*)&Pl[w][lm][f * 16 + lh * 4] = pw;
        }
        rs += __shfl_xor(rs, 16);
        rs += __shfl_xor(rs, 32);
        lS = lS * corr + rs;

        if (kt + 1 < nt) writeV(buf ^ 1);

        // redistribute corr to acc layout (q = lh*4+r)
        float cq[4];
#pragma unroll
        for (int r = 0; r < 4; ++r) cq[r] = __shfl(corr, lh * 4 + r);
#pragma unroll
        for (int df = 0; df < 4; ++df)
#pragma unroll
            for (int r = 0; r < 4; ++r) acc[df][r] *= cq[r];

        // PV: O += P @ V
#pragma unroll
        for (int kk = 0; kk < 2; ++kk) {
            bf16x8 pa = *(const bf16x8*)&Pl[w][lm][kk * 32 + lh * 8];
            const int kblk = 4 * kk + lh;
#pragma unroll
            for (int df = 0; df < 4; ++df) {
                const int dr = df * 16 + lm;
                bf16x8 vf = *(const bf16x8*)&Vt[buf][dr][((kblk ^ ((dr >> 3) & 7)) << 3)];
                acc[df] = __builtin_amdgcn_mfma_f32_16x16x32_bf16(pa, vf, acc[df], 0, 0, 0);
            }
        }
        __syncthreads();
    }

    // epilogue
    const float linv = 1.0f / lS;
    float iq[4];
#pragma unroll
    for (int r = 0; r < 4; ++r) iq[r] = __shfl(linv, lh * 4 + r);
    bf16* ob = out + (size_t)b * T * 1024 + h * 64;
#pragma unroll
    for (int r = 0; r < 4; ++r) {
        const int q = q0w + lh * 4 + r;
#pragma unroll
        for (int df = 0; df < 4; ++df)
            ob[(size_t)q * 1024 + df * 16 + lm] = (bf16)(acc[df][r] * iq[r]);
    }
}

// -----------------------------------------------------------------------------
extern "C" void kernel_launch(void* const* d_in, const int* in_sizes, int n_in,
                              void* d_out, int out_size, void* d_ws, size_t ws_size,
                              hipStream_t stream) {
    const float* x      = (const float*)d_in[0];
    const float* alpha  = (const float*)d_in[1];
    const float* gamma  = (const float*)d_in[2];
    const float* beta   = (const float*)d_in[3];
    const float* w_attn = (const float*)d_in[4];
    const float* b_attn = (const float*)d_in[5];
    const float* w_proj = (const float*)d_in[6];
    const float* b_proj = (const float*)d_in[7];
    const float* w_fc   = (const float*)d_in[8];
    const float* b_fc   = (const float*)d_in[9];
    const float* w_fc2  = (const float*)d_in[10];
    const float* b_fc2  = (const float*)d_in[11];
    float* out = (float*)d_out;

    const int M = 4096, C = 1024, F = 4096;
    char* ws = (char*)d_ws;
    bf16* wt_attn = (bf16*)ws;                        // [3C][C]   6 MB
    bf16* wt_proj = wt_attn + (size_t)3 * C * C;      // [C][C]    2 MB
    bf16* wt_fc   = wt_proj + (size_t)C * C;          // [F][C]    8 MB
    bf16* wt_fc2  = wt_fc   + (size_t)F * C;          // [C][F]    8 MB
    bf16* hbuf    = wt_fc2  + (size_t)C * F;          // [M][C]    8 MB (h, then h2)
    bf16* qkvbuf  = hbuf    + (size_t)M * C;          // [M][3C] then act [M][F] 32 MB
    bf16* aout    = qkvbuf  + (size_t)M * F;          // [M][C]    8 MB
    float* x2     = (float*)(aout + (size_t)M * C);   // [M][C]   16 MB
    float* part   = x2 + (size_t)M * C;               // 2x [M][C] f32, 32 MB
    const size_t need = (size_t)(88 + 32) * 1024 * 1024;
    const bool splitK = ws_size >= need;

    dim3 blk(256);
    conv_t_kernel<<<dim3(3 * C / 64, C / 64), blk, 0, stream>>>(w_attn, wt_attn, C, 3 * C);
    conv_t_kernel<<<dim3(C / 64, C / 64),     blk, 0, stream>>>(w_proj, wt_proj, C, C);
    conv_t_kernel<<<dim3(F / 64, C / 64),     blk, 0, stream>>>(w_fc,   wt_fc,   C, F);
    conv_t_kernel<<<dim3(C / 64, F / 64),     blk, 0, stream>>>(w_fc2,  wt_fc2,  F, C);

    dyt_kernel<<<dim3(M * C / 1024), blk, 0, stream>>>(x, alpha, gamma, beta, hbuf, M * C);

    // QKV: [M][3C] = h @ w_attn
    gemm_kernel<0><<<dim3(3 * C / 128, M / 128), blk, 0, stream>>>(
        hbuf, wt_attn, b_attn, nullptr, nullptr, qkvbuf, nullptr, nullptr, nullptr,
        M, 3 * C, C, C, C);

    attn_kernel<<<dim3(32, 32), blk, 0, stream>>>(qkvbuf, aout);

    // proj + residual(x) -> x2 (f32) and h2 = DyT(x2) (bf16, into hbuf)
    gemm_kernel<1><<<dim3(C / 128, M / 128), blk, 0, stream>>>(
        aout, wt_proj, b_proj, x, x2, hbuf, alpha, gamma, beta,
        M, C, C, C, C);

    // fc + gelu -> act (reuse qkvbuf region, [M][F])
    gemm_kernel<2><<<dim3(F / 128, M / 128), blk, 0, stream>>>(
        hbuf, wt_fc, b_fc, nullptr, nullptr, qkvbuf, nullptr, nullptr, nullptr,
        M, F, C, C, C);

    // fc2 + residual(x2) -> d_out (f32)
    if (splitK) {
        gemm_kernel<4><<<dim3(C / 128, M / 128, 2), blk, 0, stream>>>(
            qkvbuf, wt_fc2, b_fc2, nullptr, part, nullptr, nullptr, nullptr, nullptr,
            M, C, F / 2, F, F);
        reduce2_kernel<<<dim3(M * C / 1024), blk, 0, stream>>>(part, b_fc2, x2, out, M * C);
    } else {
        gemm_kernel<3><<<dim3(C / 128, M / 128), blk, 0, stream>>>(
            qkvbuf, wt_fc2, b_fc2, x2, out, nullptr, nullptr, nullptr, nullptr,
            M, C, F, F, F);
    }
}

// Round 6
// 281.295 us; speedup vs baseline: 2.2498x; 1.0092x over previous
//
#include <hip/hip_runtime.h>
#include <cstdint>
#include <cstddef>

typedef __bf16 bf16;
typedef __bf16 bf16x8 __attribute__((ext_vector_type(8)));
typedef __bf16 bf16x4 __attribute__((ext_vector_type(4)));
typedef float f32x4 __attribute__((ext_vector_type(4)));

#define DEVI __device__ __forceinline__

DEVI void gload_lds16(const bf16* g, bf16* l) {
    __builtin_amdgcn_global_load_lds(
        (const __attribute__((address_space(1))) void*)(const void*)g,
        (__attribute__((address_space(3))) void*)(void*)l, 16, 0, 0);
}

// ---------------- weight convert + transpose: W[K][N] f32 -> Wt[N][K] bf16 ----
__global__ void conv_t_kernel(const float* __restrict__ W, bf16* __restrict__ Wt,
                              int K, int N) {
    __shared__ float tile[64][65];
    const int tid = threadIdx.x;
    const int c  = tid & 63;
    const int r4 = tid >> 6;   // 0..3
    const int n0 = blockIdx.x * 64;
    const int k0 = blockIdx.y * 64;
#pragma unroll
    for (int r = 0; r < 64; r += 4)
        tile[r + r4][c] = W[(size_t)(k0 + r + r4) * N + n0 + c];
    __syncthreads();
#pragma unroll
    for (int r = 0; r < 64; r += 4)
        Wt[(size_t)(n0 + r + r4) * K + k0 + c] = (bf16)tile[c][r + r4];
}

// ---------------- DyT: h = gamma*tanh(alpha*x)+beta  (f32 -> bf16) -----------
__global__ void dyt_kernel(const float* __restrict__ x, const float* __restrict__ alpha,
                           const float* __restrict__ gamma, const float* __restrict__ beta,
                           bf16* __restrict__ h, int total) {
    int i4 = (blockIdx.x * 256 + threadIdx.x) * 4;
    if (i4 >= total) return;
    float a = alpha[0];
    float4 xv = *(const float4*)&x[i4];
    int c = i4 & 1023;
    float4 g  = *(const float4*)&gamma[c];
    float4 bt = *(const float4*)&beta[c];
    bf16x4 o;
    o[0] = (bf16)(g.x * tanhf(xv.x * a) + bt.x);
    o[1] = (bf16)(g.y * tanhf(xv.y * a) + bt.y);
    o[2] = (bf16)(g.z * tanhf(xv.z * a) + bt.z);
    o[3] = (bf16)(g.w * tanhf(xv.w * a) + bt.w);
    *(bf16x4*)&h[i4] = o;
}

// ---------------- reduce for split-K fc2: out = p0 + p1 + bias + resid -------
__global__ void reduce2_kernel(const float* __restrict__ p, const float* __restrict__ bias,
                               const float* __restrict__ resid, float* __restrict__ out,
                               int total) {
    int i4 = (blockIdx.x * 256 + threadIdx.x) * 4;
    if (i4 >= total) return;
    float4 a = *(const float4*)&p[i4];
    float4 bsec = *(const float4*)&p[(size_t)total + i4];
    float4 r = *(const float4*)&resid[i4];
    int c = i4 & 1023;
    float4 bb = *(const float4*)&bias[c];
    float4 o;
    o.x = a.x + bsec.x + r.x + bb.x;
    o.y = a.y + bsec.y + r.y + bb.y;
    o.z = a.z + bsec.z + r.z + bb.z;
    o.w = a.w + bsec.w + r.w + bb.w;
    *(float4*)&out[i4] = o;
}

// ---- reduce for split-K proj: v = p0+p1+bias+resid; xout=v; hout=DyT(v) -----
__global__ void reduce2_dyt_kernel(const float* __restrict__ p, const float* __restrict__ bias,
                                   const float* __restrict__ resid,
                                   float* __restrict__ xout, bf16* __restrict__ hout,
                                   const float* __restrict__ alpha,
                                   const float* __restrict__ gamma,
                                   const float* __restrict__ beta, int total) {
    int i4 = (blockIdx.x * 256 + threadIdx.x) * 4;
    if (i4 >= total) return;
    float a = alpha[0];
    float4 p0 = *(const float4*)&p[i4];
    float4 p1 = *(const float4*)&p[(size_t)total + i4];
    float4 r  = *(const float4*)&resid[i4];
    int c = i4 & 1023;
    float4 bb = *(const float4*)&bias[c];
    float4 g  = *(const float4*)&gamma[c];
    float4 bt = *(const float4*)&beta[c];
    float4 v;
    v.x = p0.x + p1.x + r.x + bb.x;
    v.y = p0.y + p1.y + r.y + bb.y;
    v.z = p0.z + p1.z + r.z + bb.z;
    v.w = p0.w + p1.w + r.w + bb.w;
    *(float4*)&xout[i4] = v;
    bf16x4 o;
    o[0] = (bf16)(g.x * tanhf(v.x * a) + bt.x);
    o[1] = (bf16)(g.y * tanhf(v.y * a) + bt.y);
    o[2] = (bf16)(g.z * tanhf(v.z * a) + bt.z);
    o[3] = (bf16)(g.w * tanhf(v.w * a) + bt.w);
    *(bf16x4*)&hout[i4] = o;
}

// ---------------- GEMM: C = A[M][lda] @ Wt[N][ldb]^T, 128x128x32, 4 waves ----
// 2-phase prefetch; LDS group-swizzled both-sides; bijective XCD swizzle.
// OP 0: out_bf16 = acc + bias                         (QKV)
// OP 1: v = acc+bias+resid; out_f32 = v; out_bf16 = DyT(v)
// OP 2: out_bf16 = gelu_exact(acc + bias)             (fc)
// OP 3: out_f32 = acc + bias + resid                  (full-K + resid)
// OP 4: out_f32[z*M*N + idx] = acc                    (split-K partial)
template<int OP>
__global__ void gemm_kernel(const bf16* __restrict__ A, const bf16* __restrict__ Wt,
                            const float* __restrict__ bias, const float* resid,
                            float* outf, bf16* outb,
                            const float* __restrict__ alpha_p,
                            const float* __restrict__ gamma,
                            const float* __restrict__ beta,
                            int M, int N, int K, int lda, int ldb) {
    __shared__ bf16 As[2][128 * 32];
    __shared__ bf16 Bs[2][128 * 32];
    const int tid  = threadIdx.x;
    const int lane = tid & 63;
    const int w    = tid >> 6;
    const int wr   = w >> 1, wc = w & 1;

    const int nwgx = gridDim.x;
    const int nwg  = gridDim.x * gridDim.y;
    const int orig = blockIdx.y * nwgx + blockIdx.x;
    const int cpx  = nwg >> 3;
    const int swz  = (orig & 7) * cpx + (orig >> 3);
    const int bm = (swz / nwgx) * 128;
    const int bn = (swz % nwgx) * 128;
    const int kz = blockIdx.z * K;          // split-K offset

    f32x4 acc[4][4] = {};

    const int srow = tid >> 2;
    const int sgrp = ((tid & 3) ^ ((srow >> 1) & 3)) * 8;
    const bf16* a0 = A  + (size_t)(bm + srow) * lda + kz + sgrp;
    const bf16* a1 = a0 + (size_t)64 * lda;
    const bf16* b0 = Wt + (size_t)(bn + srow) * ldb + kz + sgrp;
    const bf16* b1 = b0 + (size_t)64 * ldb;

    auto stage = [&](int buf) {
        gload_lds16(a0, &As[buf][tid * 8]);
        gload_lds16(a1, &As[buf][2048 + tid * 8]);
        gload_lds16(b0, &Bs[buf][tid * 8]);
        gload_lds16(b1, &Bs[buf][2048 + tid * 8]);
        a0 += 32; a1 += 32; b0 += 32; b1 += 32;
    };

    const int lh = lane >> 4, lm = lane & 15;
    const int arow = wr * 64 + lm;
    const int brow = wc * 64 + lm;
    const int gsw = (lh ^ ((lm >> 1) & 3)) * 8;   // swizzled group offset

    stage(0);
    __syncthreads();

    const int nk = K >> 5;
    for (int kt = 0; kt < nk; ++kt) {
        const int cur = kt & 1;
        if (kt + 1 < nk) stage(cur ^ 1);
        bf16x8 af[4], bfr[4];
#pragma unroll
        for (int i = 0; i < 4; i++)
            af[i] = *(const bf16x8*)&As[cur][(arow + i * 16) * 32 + gsw];
#pragma unroll
        for (int i = 0; i < 4; i++)
            bfr[i] = *(const bf16x8*)&Bs[cur][(brow + i * 16) * 32 + gsw];
#pragma unroll
        for (int i = 0; i < 4; i++)
#pragma unroll
            for (int j = 0; j < 4; j++)
                acc[i][j] = __builtin_amdgcn_mfma_f32_16x16x32_bf16(af[i], bfr[j], acc[i][j], 0, 0, 0);
        __syncthreads();
    }

#pragma unroll
    for (int i = 0; i < 4; i++) {
        const int row0 = bm + wr * 64 + i * 16 + lh * 4;
#pragma unroll
        for (int jf = 0; jf < 4; jf++) {
            const int col = bn + wc * 64 + jf * 16 + lm;
            const float bval = (OP == 4) ? 0.f : bias[col];
#pragma unroll
            for (int r = 0; r < 4; r++) {
                const int row = row0 + r;
                const size_t idx = (size_t)row * N + col;
                float v = acc[i][jf][r] + bval;
                if (OP == 0) {
                    outb[idx] = (bf16)v;
                } else if (OP == 1) {
                    v += resid[idx];
                    outf[idx] = v;
                    float hh = gamma[col] * tanhf(v * alpha_p[0]) + beta[col];
                    outb[idx] = (bf16)hh;
                } else if (OP == 2) {
                    float g = 0.5f * v * (1.0f + erff(v * 0.70710678118f));
                    outb[idx] = (bf16)g;
                } else if (OP == 3) {
                    v += resid[idx];
                    outf[idx] = v;
                } else {
                    outf[(size_t)blockIdx.z * M * N + idx] = v;
                }
            }
        }
    }
}

// ---------------- causal flash attention, H=16 D=64 T=2048 -------------------
// LPT order; K staged via dbuf global_load_lds (swizzled); V reg-staged
// transposed. Swapped QK^T AND swapped PV -> O^T accumulator: softmax stats,
// corr rescale, and 1/l all in-lane (q = lane&15). exp2-domain softmax.
__global__ void attn_kernel(const bf16* __restrict__ qkv, bf16* __restrict__ out) {
    const int bq = (gridDim.x - 1) - blockIdx.x;   // heavy tiles first (LPT)
    const int bh = blockIdx.y;                     // b*16 + h
    const int b = bh >> 4, h = bh & 15;
    const int tid = threadIdx.x, lane = tid & 63, w = tid >> 6;
    const int T = 2048;
    const size_t C3 = 3072;
    const bf16* qb = qkv + (size_t)b * T * C3 + h * 64;
    const bf16* kb = qb + 1024;
    const bf16* vb = qb + 2048;

    __shared__ bf16 Ks[2][64][64];      // [buf][kv][d], d-blocks XOR-swizzled by kv&7
    __shared__ bf16 Vt[2][64][72];      // [buf][d][k-swizzled]
    __shared__ bf16 Pl[4][16][72];      // per-wave P [q][k]

    const int q0w = bq * 64 + w * 16;
    const int lm = lane & 15;
    const int lh = lane >> 4;

    bf16x8 qf0, qf1;
    {
        size_t qoff = (size_t)(q0w + lm) * C3 + lh * 8;
        qf0 = *(const bf16x8*)&qb[qoff];
        qf1 = *(const bf16x8*)&qb[qoff + 32];
    }
    f32x4 acc[4] = {};                  // O^T: acc[df][r] = O[q=lm][d=df*16+lh*4+r]
    float mS = -1e30f, lS = 0.f;        // stats for q = q0w+lm (in-lane)

    const float SC = 0.125f * 1.44269504089f;   // scale * log2(e)

    const int nt = bq + 1;
    const int sg = tid & 7;             // d-group (8 rows of Vt)
    const int sq = tid >> 3;            // k-quad, valid 0..15 for tid<128
    bf16x8 rv[4];

    const int krow = tid >> 3;
    const int kcb  = tid & 7;
    const int kcbs = (kcb ^ (krow & 7)) * 8;
    auto stageK = [&](int buf, int k0) {
        gload_lds16(&kb[(size_t)(k0 + krow) * C3 + kcbs],      &Ks[buf][0][0]  + tid * 8);
        gload_lds16(&kb[(size_t)(k0 + 32 + krow) * C3 + kcbs], &Ks[buf][32][0] + tid * 8);
    };
    auto loadV = [&](int k0) {
        if (tid < 128) {
#pragma unroll
            for (int i = 0; i < 4; ++i)
                rv[i] = *(const bf16x8*)&vb[(size_t)(k0 + sq * 4 + i) * C3 + sg * 8];
        }
    };
    auto writeV = [&](int buf) {
        if (tid < 128) {
            const int cbase = ((((sq >> 1) ^ sg) & 7) << 3) + ((sq & 1) << 2);
#pragma unroll
            for (int e = 0; e < 8; ++e) {
                bf16x4 wv;
                wv[0] = rv[0][e]; wv[1] = rv[1][e]; wv[2] = rv[2][e]; wv[3] = rv[3][e];
                *(bf16x4*)&Vt[buf][sg * 8 + e][cbase] = wv;
            }
        }
    };

    stageK(0, 0);
    loadV(0);
    writeV(0);
    __syncthreads();

    for (int kt = 0; kt < nt; ++kt) {
        const int k0 = kt * 64;
        const int buf = kt & 1;
        if (kt + 1 < nt) {
            stageK(buf ^ 1, k0 + 64);
            loadV(k0 + 64);
        }

        // S^T fragments from LDS K: s[f][r] = S[k0+f*16+lh*4+r][q0w+lm]
        f32x4 s[4];
#pragma unroll
        for (int f = 0; f < 4; ++f) {
            const int row = f * 16 + lm;
            const int sw = (row & 7);
            bf16x8 kf0v = *(const bf16x8*)&Ks[buf][row][(lh ^ sw) * 8];
            bf16x8 kf1v = *(const bf16x8*)&Ks[buf][row][((lh + 4) ^ sw) * 8];
            f32x4 z = {};
            z = __builtin_amdgcn_mfma_f32_16x16x32_bf16(kf0v, qf0, z, 0, 0, 0);
            z = __builtin_amdgcn_mfma_f32_16x16x32_bf16(kf1v, qf1, z, 0, 0, 0);
            s[f] = z;
        }
        const int qg = q0w + lm;
        if (kt == bq) {
#pragma unroll
            for (int f = 0; f < 4; ++f)
#pragma unroll
                for (int r = 0; r < 4; ++r) {
                    const int kgl = k0 + f * 16 + lh * 4 + r;
                    float v = s[f][r] * SC;
                    s[f][r] = (kgl > qg) ? -1e30f : v;
                }
        } else {
#pragma unroll
            for (int f = 0; f < 4; ++f)
#pragma unroll
                for (int r = 0; r < 4; ++r) s[f][r] *= SC;
        }

        // online softmax (base-2) for row q = qg: in-lane + 2 shfl
        float m0 = fmaxf(fmaxf(s[0][0], s[0][1]), fmaxf(s[0][2], s[0][3]));
        float m1 = fmaxf(fmaxf(s[1][0], s[1][1]), fmaxf(s[1][2], s[1][3]));
        float m2 = fmaxf(fmaxf(s[2][0], s[2][1]), fmaxf(s[2][2], s[2][3]));
        float m3 = fmaxf(fmaxf(s[3][0], s[3][1]), fmaxf(s[3][2], s[3][3]));
        float pm = fmaxf(fmaxf(m0, m1), fmaxf(m2, m3));
        pm = fmaxf(pm, __shfl_xor(pm, 16));
        pm = fmaxf(pm, __shfl_xor(pm, 32));
        const float mnew = fmaxf(mS, pm);
        const float corr = exp2f(mS - mnew);
        mS = mnew;

        float rs = 0.f;
#pragma unroll
        for (int f = 0; f < 4; ++f) {
            bf16x4 pw;
#pragma unroll
            for (int r = 0; r < 4; ++r) {
                const float pv = exp2f(s[f][r] - mnew);
                rs += pv;
                pw[r] = (bf16)pv;
            }
            *(bf16x4*)&Pl[w][lm][f * 16 + lh * 4] = pw;
        }
        rs += __shfl_xor(rs, 16);
        rs += __shfl_xor(rs, 32);
        lS = lS * corr + rs;

        if (kt + 1 < nt) writeV(buf ^ 1);

        // rescale O^T accumulator in-lane (q = lm)
#pragma unroll
        for (int df = 0; df < 4; ++df)
#pragma unroll
            for (int r = 0; r < 4; ++r) acc[df][r] *= corr;

        // PV swapped: acc[df][r] = O[q=lm][d=df*16+lh*4+r]
#pragma unroll
        for (int kk = 0; kk < 2; ++kk) {
            bf16x8 pa = *(const bf16x8*)&Pl[w][lm][kk * 32 + lh * 8];
            const int kblk = 4 * kk + lh;
#pragma unroll
            for (int df = 0; df < 4; ++df) {
                const int dr = df * 16 + lm;
                bf16x8 vf = *(const bf16x8*)&Vt[buf][dr][((kblk ^ ((dr >> 3) & 7)) << 3)];
                acc[df] = __builtin_amdgcn_mfma_f32_16x16x32_bf16(vf, pa, acc[df], 0, 0, 0);
            }
        }
        __syncthreads();
    }

    // epilogue: in-lane normalize, per-row bf16x4 stores
    const float linv = 1.0f / lS;
    bf16* ob = out + (size_t)b * T * 1024 + h * 64 + (size_t)(q0w + lm) * 1024;
#pragma unroll
    for (int df = 0; df < 4; ++df) {
        bf16x4 st;
#pragma unroll
        for (int r = 0; r < 4; ++r) st[r] = (bf16)(acc[df][r] * linv);
        *(bf16x4*)&ob[df * 16 + lh * 4] = st;
    }
}

// -----------------------------------------------------------------------------
extern "C" void kernel_launch(void* const* d_in, const int* in_sizes, int n_in,
                              void* d_out, int out_size, void* d_ws, size_t ws_size,
                              hipStream_t stream) {
    const float* x      = (const float*)d_in[0];
    const float* alpha  = (const float*)d_in[1];
    const float* gamma  = (const float*)d_in[2];
    const float* beta   = (const float*)d_in[3];
    const float* w_attn = (const float*)d_in[4];
    const float* b_attn = (const float*)d_in[5];
    const float* w_proj = (const float*)d_in[6];
    const float* b_proj = (const float*)d_in[7];
    const float* w_fc   = (const float*)d_in[8];
    const float* b_fc   = (const float*)d_in[9];
    const float* w_fc2  = (const float*)d_in[10];
    const float* b_fc2  = (const float*)d_in[11];
    float* out = (float*)d_out;

    const int M = 4096, C = 1024, F = 4096;
    char* ws = (char*)d_ws;
    bf16* wt_attn = (bf16*)ws;                        // [3C][C]   6 MB
    bf16* wt_proj = wt_attn + (size_t)3 * C * C;      // [C][C]    2 MB
    bf16* wt_fc   = wt_proj + (size_t)C * C;          // [F][C]    8 MB
    bf16* wt_fc2  = wt_fc   + (size_t)F * C;          // [C][F]    8 MB
    bf16* hbuf    = wt_fc2  + (size_t)C * F;          // [M][C]    8 MB (h, then h2)
    bf16* qkvbuf  = hbuf    + (size_t)M * C;          // [M][3C] then act [M][F] 32 MB
    bf16* aout    = qkvbuf  + (size_t)M * F;          // [M][C]    8 MB
    float* x2     = (float*)(aout + (size_t)M * C);   // [M][C]   16 MB
    float* part   = x2 + (size_t)M * C;               // 2x [M][C] f32, 32 MB
    const size_t need = (size_t)(88 + 32) * 1024 * 1024;
    const bool splitK = ws_size >= need;

    dim3 blk(256);
    conv_t_kernel<<<dim3(3 * C / 64, C / 64), blk, 0, stream>>>(w_attn, wt_attn, C, 3 * C);
    conv_t_kernel<<<dim3(C / 64, C / 64),     blk, 0, stream>>>(w_proj, wt_proj, C, C);
    conv_t_kernel<<<dim3(F / 64, C / 64),     blk, 0, stream>>>(w_fc,   wt_fc,   C, F);
    conv_t_kernel<<<dim3(C / 64, F / 64),     blk, 0, stream>>>(w_fc2,  wt_fc2,  F, C);

    dyt_kernel<<<dim3(M * C / 1024), blk, 0, stream>>>(x, alpha, gamma, beta, hbuf, M * C);

    // QKV: [M][3C] = h @ w_attn
    gemm_kernel<0><<<dim3(3 * C / 128, M / 128), blk, 0, stream>>>(
        hbuf, wt_attn, b_attn, nullptr, nullptr, qkvbuf, nullptr, nullptr, nullptr,
        M, 3 * C, C, C, C);

    attn_kernel<<<dim3(32, 32), blk, 0, stream>>>(qkvbuf, aout);

    // proj + residual(x) -> x2 (f32) and h2 = DyT(x2) (bf16, into hbuf)
    if (splitK) {
        gemm_kernel<4><<<dim3(C / 128, M / 128, 2), blk, 0, stream>>>(
            aout, wt_proj, b_proj, nullptr, part, nullptr, nullptr, nullptr, nullptr,
            M, C, C / 2, C, C);
        reduce2_dyt_kernel<<<dim3(M * C / 1024), blk, 0, stream>>>(
            part, b_proj, x, x2, hbuf, alpha, gamma, beta, M * C);
    } else {
        gemm_kernel<1><<<dim3(C / 128, M / 128), blk, 0, stream>>>(
            aout, wt_proj, b_proj, x, x2, hbuf, alpha, gamma, beta,
            M, C, C, C, C);
    }

    // fc + gelu -> act (reuse qkvbuf region, [M][F])
    gemm_kernel<2><<<dim3(F / 128, M / 128), blk, 0, stream>>>(
        hbuf, wt_fc, b_fc, nullptr, nullptr, qkvbuf, nullptr, nullptr, nullptr,
        M, F, C, C, C);

    // fc2 + residual(x2) -> d_out (f32)
    if (splitK) {
        gemm_kernel<4><<<dim3(C / 128, M / 128, 2), blk, 0, stream>>>(
            qkvbuf, wt_fc2, b_fc2, nullptr, part, nullptr, nullptr, nullptr, nullptr,
            M, C, F / 2, F, F);
        reduce2_kernel<<<dim3(M * C / 1024), blk, 0, stream>>>(part, b_fc2, x2, out, M * C);
    } else {
        gemm_kernel<3><<<dim3(C / 128, M / 128), blk, 0, stream>>>(
            qkvbuf, wt_fc2, b_fc2, x2, out, nullptr, nullptr, nullptr, nullptr,
            M, C, F, F, F);
    }
}

// Round 7
// 272.956 us; speedup vs baseline: 2.3185x; 1.0306x over previous
//
#include <hip/hip_runtime.h>
#include <cstdint>
#include <cstddef>

typedef __bf16 bf16;
typedef __bf16 bf16x8 __attribute__((ext_vector_type(8)));
typedef __bf16 bf16x4 __attribute__((ext_vector_type(4)));
typedef float f32x4 __attribute__((ext_vector_type(4)));

#define DEVI __device__ __forceinline__

DEVI void gload_lds16(const bf16* g, bf16* l) {
    __builtin_amdgcn_global_load_lds(
        (const __attribute__((address_space(1))) void*)(const void*)g,
        (__attribute__((address_space(3))) void*)(void*)l, 16, 0, 0);
}

// ---------------- weight convert + transpose: W[K][N] f32 -> Wt[N][K] bf16 ----
__global__ void conv_t_kernel(const float* __restrict__ W, bf16* __restrict__ Wt,
                              int K, int N) {
    __shared__ float tile[64][65];
    const int tid = threadIdx.x;
    const int c  = tid & 63;
    const int r4 = tid >> 6;   // 0..3
    const int n0 = blockIdx.x * 64;
    const int k0 = blockIdx.y * 64;
#pragma unroll
    for (int r = 0; r < 64; r += 4)
        tile[r + r4][c] = W[(size_t)(k0 + r + r4) * N + n0 + c];
    __syncthreads();
#pragma unroll
    for (int r = 0; r < 64; r += 4)
        Wt[(size_t)(n0 + r + r4) * K + k0 + c] = (bf16)tile[c][r + r4];
}

// ---------------- DyT: h = gamma*tanh(alpha*x)+beta  (f32 -> bf16) -----------
__global__ void dyt_kernel(const float* __restrict__ x, const float* __restrict__ alpha,
                           const float* __restrict__ gamma, const float* __restrict__ beta,
                           bf16* __restrict__ h, int total) {
    int i4 = (blockIdx.x * 256 + threadIdx.x) * 4;
    if (i4 >= total) return;
    float a = alpha[0];
    float4 xv = *(const float4*)&x[i4];
    int c = i4 & 1023;
    float4 g  = *(const float4*)&gamma[c];
    float4 bt = *(const float4*)&beta[c];
    bf16x4 o;
    o[0] = (bf16)(g.x * tanhf(xv.x * a) + bt.x);
    o[1] = (bf16)(g.y * tanhf(xv.y * a) + bt.y);
    o[2] = (bf16)(g.z * tanhf(xv.z * a) + bt.z);
    o[3] = (bf16)(g.w * tanhf(xv.w * a) + bt.w);
    *(bf16x4*)&h[i4] = o;
}

// ---------------- reduce for split-K fc2: out = p0 + p1 + bias + resid -------
__global__ void reduce2_kernel(const float* __restrict__ p, const float* __restrict__ bias,
                               const float* __restrict__ resid, float* __restrict__ out,
                               int total) {
    int i4 = (blockIdx.x * 256 + threadIdx.x) * 4;
    if (i4 >= total) return;
    float4 a = *(const float4*)&p[i4];
    float4 bsec = *(const float4*)&p[(size_t)total + i4];
    float4 r = *(const float4*)&resid[i4];
    int c = i4 & 1023;
    float4 bb = *(const float4*)&bias[c];
    float4 o;
    o.x = a.x + bsec.x + r.x + bb.x;
    o.y = a.y + bsec.y + r.y + bb.y;
    o.z = a.z + bsec.z + r.z + bb.z;
    o.w = a.w + bsec.w + r.w + bb.w;
    *(float4*)&out[i4] = o;
}

// ---- reduce for split-K proj: v = p0+p1+bias+resid; xout=v; hout=DyT(v) -----
__global__ void reduce2_dyt_kernel(const float* __restrict__ p, const float* __restrict__ bias,
                                   const float* __restrict__ resid,
                                   float* __restrict__ xout, bf16* __restrict__ hout,
                                   const float* __restrict__ alpha,
                                   const float* __restrict__ gamma,
                                   const float* __restrict__ beta, int total) {
    int i4 = (blockIdx.x * 256 + threadIdx.x) * 4;
    if (i4 >= total) return;
    float a = alpha[0];
    float4 p0 = *(const float4*)&p[i4];
    float4 p1 = *(const float4*)&p[(size_t)total + i4];
    float4 r  = *(const float4*)&resid[i4];
    int c = i4 & 1023;
    float4 bb = *(const float4*)&bias[c];
    float4 g  = *(const float4*)&gamma[c];
    float4 bt = *(const float4*)&beta[c];
    float4 v;
    v.x = p0.x + p1.x + r.x + bb.x;
    v.y = p0.y + p1.y + r.y + bb.y;
    v.z = p0.z + p1.z + r.z + bb.z;
    v.w = p0.w + p1.w + r.w + bb.w;
    *(float4*)&xout[i4] = v;
    bf16x4 o;
    o[0] = (bf16)(g.x * tanhf(v.x * a) + bt.x);
    o[1] = (bf16)(g.y * tanhf(v.y * a) + bt.y);
    o[2] = (bf16)(g.z * tanhf(v.z * a) + bt.z);
    o[3] = (bf16)(g.w * tanhf(v.w * a) + bt.w);
    *(bf16x4*)&hout[i4] = o;
}

// ---------------- GEMM: C = A[M][lda] @ Wt[N][ldb]^T, 128x128x32, 4 waves ----
// 2-phase prefetch; LDS group-swizzled both-sides; bijective XCD swizzle.
// OP 0: out_bf16 = (acc + bias) * (col<1024 ? 0.125*log2e : 1)   (QKV, Q pre-scaled)
// OP 1: v = acc+bias+resid; out_f32 = v; out_bf16 = DyT(v)
// OP 2: out_bf16 = gelu_exact(acc + bias)             (fc)
// OP 3: out_f32 = acc + bias + resid                  (full-K + resid)
// OP 4: out_f32[z*M*N + idx] = acc                    (split-K partial)
template<int OP>
__global__ void gemm_kernel(const bf16* __restrict__ A, const bf16* __restrict__ Wt,
                            const float* __restrict__ bias, const float* resid,
                            float* outf, bf16* outb,
                            const float* __restrict__ alpha_p,
                            const float* __restrict__ gamma,
                            const float* __restrict__ beta,
                            int M, int N, int K, int lda, int ldb) {
    __shared__ bf16 As[2][128 * 32];
    __shared__ bf16 Bs[2][128 * 32];
    const int tid  = threadIdx.x;
    const int lane = tid & 63;
    const int w    = tid >> 6;
    const int wr   = w >> 1, wc = w & 1;

    const int nwgx = gridDim.x;
    const int nwg  = gridDim.x * gridDim.y;
    const int orig = blockIdx.y * nwgx + blockIdx.x;
    const int cpx  = nwg >> 3;
    const int swz  = (orig & 7) * cpx + (orig >> 3);
    const int bm = (swz / nwgx) * 128;
    const int bn = (swz % nwgx) * 128;
    const int kz = blockIdx.z * K;          // split-K offset

    f32x4 acc[4][4] = {};

    const int srow = tid >> 2;
    const int sgrp = ((tid & 3) ^ ((srow >> 1) & 3)) * 8;
    const bf16* a0 = A  + (size_t)(bm + srow) * lda + kz + sgrp;
    const bf16* a1 = a0 + (size_t)64 * lda;
    const bf16* b0 = Wt + (size_t)(bn + srow) * ldb + kz + sgrp;
    const bf16* b1 = b0 + (size_t)64 * ldb;

    auto stage = [&](int buf) {
        gload_lds16(a0, &As[buf][tid * 8]);
        gload_lds16(a1, &As[buf][2048 + tid * 8]);
        gload_lds16(b0, &Bs[buf][tid * 8]);
        gload_lds16(b1, &Bs[buf][2048 + tid * 8]);
        a0 += 32; a1 += 32; b0 += 32; b1 += 32;
    };

    const int lh = lane >> 4, lm = lane & 15;
    const int arow = wr * 64 + lm;
    const int brow = wc * 64 + lm;
    const int gsw = (lh ^ ((lm >> 1) & 3)) * 8;   // swizzled group offset

    stage(0);
    __syncthreads();

    const int nk = K >> 5;
    for (int kt = 0; kt < nk; ++kt) {
        const int cur = kt & 1;
        if (kt + 1 < nk) stage(cur ^ 1);
        bf16x8 af[4], bfr[4];
#pragma unroll
        for (int i = 0; i < 4; i++)
            af[i] = *(const bf16x8*)&As[cur][(arow + i * 16) * 32 + gsw];
#pragma unroll
        for (int i = 0; i < 4; i++)
            bfr[i] = *(const bf16x8*)&Bs[cur][(brow + i * 16) * 32 + gsw];
#pragma unroll
        for (int i = 0; i < 4; i++)
#pragma unroll
            for (int j = 0; j < 4; j++)
                acc[i][j] = __builtin_amdgcn_mfma_f32_16x16x32_bf16(af[i], bfr[j], acc[i][j], 0, 0, 0);
        __syncthreads();
    }

#pragma unroll
    for (int i = 0; i < 4; i++) {
        const int row0 = bm + wr * 64 + i * 16 + lh * 4;
#pragma unroll
        for (int jf = 0; jf < 4; jf++) {
            const int col = bn + wc * 64 + jf * 16 + lm;
            const float bval = (OP == 4) ? 0.f : bias[col];
#pragma unroll
            for (int r = 0; r < 4; r++) {
                const int row = row0 + r;
                const size_t idx = (size_t)row * N + col;
                float v = acc[i][jf][r] + bval;
                if (OP == 0) {
                    const float qs = (col < 1024) ? 0.18033688011f : 1.0f; // 0.125*log2(e)
                    outb[idx] = (bf16)(v * qs);
                } else if (OP == 1) {
                    v += resid[idx];
                    outf[idx] = v;
                    float hh = gamma[col] * tanhf(v * alpha_p[0]) + beta[col];
                    outb[idx] = (bf16)hh;
                } else if (OP == 2) {
                    float g = 0.5f * v * (1.0f + erff(v * 0.70710678118f));
                    outb[idx] = (bf16)g;
                } else if (OP == 3) {
                    v += resid[idx];
                    outf[idx] = v;
                } else {
                    outf[(size_t)blockIdx.z * M * N + idx] = v;
                }
            }
        }
    }
}

// ---------------- causal flash attention, H=16 D=64 T=2048 -------------------
// LPT order; K staged via dbuf global_load_lds (swizzled); V reg-staged
// transposed. Swapped QK^T AND swapped PV -> O^T accumulator: stats, rescale,
// 1/l all in-lane. Q comes pre-scaled by 0.125*log2e (folded into QKV GEMM),
// so S is already in exp2 domain. Defer-max (THR=8) skips most rescales.
__global__ void attn_kernel(const bf16* __restrict__ qkv, bf16* __restrict__ out) {
    const int bq = (gridDim.x - 1) - blockIdx.x;   // heavy tiles first (LPT)
    const int bh = blockIdx.y;                     // b*16 + h
    const int b = bh >> 4, h = bh & 15;
    const int tid = threadIdx.x, lane = tid & 63, w = tid >> 6;
    const int T = 2048;
    const size_t C3 = 3072;
    const bf16* qb = qkv + (size_t)b * T * C3 + h * 64;
    const bf16* kb = qb + 1024;
    const bf16* vb = qb + 2048;

    __shared__ bf16 Ks[2][64][64];      // [buf][kv][d], d-blocks XOR-swizzled by kv&7
    __shared__ bf16 Vt[2][64][72];      // [buf][d][k-swizzled]
    __shared__ bf16 Pl[4][16][80];      // per-wave P [q][k], 80-stride (bank spread)

    const int q0w = bq * 64 + w * 16;
    const int lm = lane & 15;
    const int lh = lane >> 4;

    bf16x8 qf0, qf1;
    {
        size_t qoff = (size_t)(q0w + lm) * C3 + lh * 8;
        qf0 = *(const bf16x8*)&qb[qoff];
        qf1 = *(const bf16x8*)&qb[qoff + 32];
    }
    f32x4 acc[4] = {};                  // O^T: acc[df][r] = O[q=lm][d=df*16+lh*4+r]
    float mS = -1e30f, lS = 0.f;        // stats for q = q0w+lm (in-lane)

    const int nt = bq + 1;
    const int sg = tid & 7;             // d-group (8 rows of Vt)
    const int sq = tid >> 3;            // k-quad, valid 0..15 for tid<128
    bf16x8 rv[4];

    const int krow = tid >> 3;
    const int kcb  = tid & 7;
    const int kcbs = (kcb ^ (krow & 7)) * 8;
    auto stageK = [&](int buf, int k0) {
        gload_lds16(&kb[(size_t)(k0 + krow) * C3 + kcbs],      &Ks[buf][0][0]  + tid * 8);
        gload_lds16(&kb[(size_t)(k0 + 32 + krow) * C3 + kcbs], &Ks[buf][32][0] + tid * 8);
    };
    auto loadV = [&](int k0) {
        if (tid < 128) {
#pragma unroll
            for (int i = 0; i < 4; ++i)
                rv[i] = *(const bf16x8*)&vb[(size_t)(k0 + sq * 4 + i) * C3 + sg * 8];
        }
    };
    auto writeV = [&](int buf) {
        if (tid < 128) {
            const int cbase = ((((sq >> 1) ^ sg) & 7) << 3) + ((sq & 1) << 2);
#pragma unroll
            for (int e = 0; e < 8; ++e) {
                bf16x4 wv;
                wv[0] = rv[0][e]; wv[1] = rv[1][e]; wv[2] = rv[2][e]; wv[3] = rv[3][e];
                *(bf16x4*)&Vt[buf][sg * 8 + e][cbase] = wv;
            }
        }
    };

    stageK(0, 0);
    loadV(0);
    writeV(0);
    __syncthreads();

    for (int kt = 0; kt < nt; ++kt) {
        const int k0 = kt * 64;
        const int buf = kt & 1;
        if (kt + 1 < nt) {
            stageK(buf ^ 1, k0 + 64);
            loadV(k0 + 64);
        }

        // S^T fragments from LDS K: s[f][r] = S[k0+f*16+lh*4+r][q0w+lm]
        // (already in exp2 domain; Q was pre-scaled)
        f32x4 s[4];
#pragma unroll
        for (int f = 0; f < 4; ++f) {
            const int row = f * 16 + lm;
            const int sw = (row & 7);
            bf16x8 kf0v = *(const bf16x8*)&Ks[buf][row][(lh ^ sw) * 8];
            bf16x8 kf1v = *(const bf16x8*)&Ks[buf][row][((lh + 4) ^ sw) * 8];
            f32x4 z = {};
            z = __builtin_amdgcn_mfma_f32_16x16x32_bf16(kf0v, qf0, z, 0, 0, 0);
            z = __builtin_amdgcn_mfma_f32_16x16x32_bf16(kf1v, qf1, z, 0, 0, 0);
            s[f] = z;
        }
        const int qg = q0w + lm;
        if (kt == bq) {     // diagonal tile: causal mask only (no scale needed)
#pragma unroll
            for (int f = 0; f < 4; ++f)
#pragma unroll
                for (int r = 0; r < 4; ++r) {
                    const int kgl = k0 + f * 16 + lh * 4 + r;
                    s[f][r] = (kgl > qg) ? -1e30f : s[f][r];
                }
        }

        // row max via max3 tree (8 instrs) + 2 shfl
        float a0 = fmaxf(fmaxf(s[0][0], s[0][1]), s[0][2]);
        float a1 = fmaxf(fmaxf(s[0][3], s[1][0]), s[1][1]);
        float a2 = fmaxf(fmaxf(s[1][2], s[1][3]), s[2][0]);
        float a3 = fmaxf(fmaxf(s[2][1], s[2][2]), s[2][3]);
        float a4 = fmaxf(fmaxf(s[3][0], s[3][1]), s[3][2]);
        float b0 = fmaxf(fmaxf(a0, a1), a2);
        float b1 = fmaxf(fmaxf(a3, a4), s[3][3]);
        float pm = fmaxf(b0, b1);
        pm = fmaxf(pm, __shfl_xor(pm, 16));
        pm = fmaxf(pm, __shfl_xor(pm, 32));

        // defer-max: only rescale when the running max grew by > 8 (log2)
        if (!__all(pm - mS <= 8.f)) {
            const float mnew = fmaxf(mS, pm);
            const float corr = __builtin_amdgcn_exp2f(mS - mnew);
            mS = mnew;
            lS *= corr;
#pragma unroll
            for (int df = 0; df < 4; ++df)
#pragma unroll
                for (int r = 0; r < 4; ++r) acc[df][r] *= corr;
        }

        float rs = 0.f;
#pragma unroll
        for (int f = 0; f < 4; ++f) {
            bf16x4 pw;
#pragma unroll
            for (int r = 0; r < 4; ++r) {
                const float pv = __builtin_amdgcn_exp2f(s[f][r] - mS);
                rs += pv;
                pw[r] = (bf16)pv;
            }
            *(bf16x4*)&Pl[w][lm][f * 16 + lh * 4] = pw;
        }
        rs += __shfl_xor(rs, 16);
        rs += __shfl_xor(rs, 32);
        lS += rs;

        if (kt + 1 < nt) writeV(buf ^ 1);

        // PV swapped: acc[df][r] = O[q=lm][d=df*16+lh*4+r]
#pragma unroll
        for (int kk = 0; kk < 2; ++kk) {
            bf16x8 pa = *(const bf16x8*)&Pl[w][lm][kk * 32 + lh * 8];
            const int kblk = 4 * kk + lh;
#pragma unroll
            for (int df = 0; df < 4; ++df) {
                const int dr = df * 16 + lm;
                bf16x8 vf = *(const bf16x8*)&Vt[buf][dr][((kblk ^ ((dr >> 3) & 7)) << 3)];
                acc[df] = __builtin_amdgcn_mfma_f32_16x16x32_bf16(vf, pa, acc[df], 0, 0, 0);
            }
        }
        __syncthreads();
    }

    // epilogue: in-lane normalize, per-row bf16x4 stores
    const float linv = 1.0f / lS;
    bf16* ob = out + (size_t)b * T * 1024 + h * 64 + (size_t)(q0w + lm) * 1024;
#pragma unroll
    for (int df = 0; df < 4; ++df) {
        bf16x4 st;
#pragma unroll
        for (int r = 0; r < 4; ++r) st[r] = (bf16)(acc[df][r] * linv);
        *(bf16x4*)&ob[df * 16 + lh * 4] = st;
    }
}

// -----------------------------------------------------------------------------
extern "C" void kernel_launch(void* const* d_in, const int* in_sizes, int n_in,
                              void* d_out, int out_size, void* d_ws, size_t ws_size,
                              hipStream_t stream) {
    const float* x      = (const float*)d_in[0];
    const float* alpha  = (const float*)d_in[1];
    const float* gamma  = (const float*)d_in[2];
    const float* beta   = (const float*)d_in[3];
    const float* w_attn = (const float*)d_in[4];
    const float* b_attn = (const float*)d_in[5];
    const float* w_proj = (const float*)d_in[6];
    const float* b_proj = (const float*)d_in[7];
    const float* w_fc   = (const float*)d_in[8];
    const float* b_fc   = (const float*)d_in[9];
    const float* w_fc2  = (const float*)d_in[10];
    const float* b_fc2  = (const float*)d_in[11];
    float* out = (float*)d_out;

    const int M = 4096, C = 1024, F = 4096;
    char* ws = (char*)d_ws;
    bf16* wt_attn = (bf16*)ws;                        // [3C][C]   6 MB
    bf16* wt_proj = wt_attn + (size_t)3 * C * C;      // [C][C]    2 MB
    bf16* wt_fc   = wt_proj + (size_t)C * C;          // [F][C]    8 MB
    bf16* wt_fc2  = wt_fc   + (size_t)F * C;          // [C][F]    8 MB
    bf16* hbuf    = wt_fc2  + (size_t)C * F;          // [M][C]    8 MB (h, then h2)
    bf16* qkvbuf  = hbuf    + (size_t)M * C;          // [M][3C] then act [M][F] 32 MB
    bf16* aout    = qkvbuf  + (size_t)M * F;          // [M][C]    8 MB
    float* x2     = (float*)(aout + (size_t)M * C);   // [M][C]   16 MB
    float* part   = x2 + (size_t)M * C;               // 2x [M][C] f32, 32 MB
    const size_t need = (size_t)(88 + 32) * 1024 * 1024;
    const bool splitK = ws_size >= need;

    dim3 blk(256);
    conv_t_kernel<<<dim3(3 * C / 64, C / 64), blk, 0, stream>>>(w_attn, wt_attn, C, 3 * C);
    conv_t_kernel<<<dim3(C / 64, C / 64),     blk, 0, stream>>>(w_proj, wt_proj, C, C);
    conv_t_kernel<<<dim3(F / 64, C / 64),     blk, 0, stream>>>(w_fc,   wt_fc,   C, F);
    conv_t_kernel<<<dim3(C / 64, F / 64),     blk, 0, stream>>>(w_fc2,  wt_fc2,  F, C);

    dyt_kernel<<<dim3(M * C / 1024), blk, 0, stream>>>(x, alpha, gamma, beta, hbuf, M * C);

    // QKV: [M][3C] = h @ w_attn  (Q columns pre-scaled by 0.125*log2e)
    gemm_kernel<0><<<dim3(3 * C / 128, M / 128), blk, 0, stream>>>(
        hbuf, wt_attn, b_attn, nullptr, nullptr, qkvbuf, nullptr, nullptr, nullptr,
        M, 3 * C, C, C, C);

    attn_kernel<<<dim3(32, 32), blk, 0, stream>>>(qkvbuf, aout);

    // proj + residual(x) -> x2 (f32) and h2 = DyT(x2) (bf16, into hbuf)
    if (splitK) {
        gemm_kernel<4><<<dim3(C / 128, M / 128, 2), blk, 0, stream>>>(
            aout, wt_proj, b_proj, nullptr, part, nullptr, nullptr, nullptr, nullptr,
            M, C, C / 2, C, C);
        reduce2_dyt_kernel<<<dim3(M * C / 1024), blk, 0, stream>>>(
            part, b_proj, x, x2, hbuf, alpha, gamma, beta, M * C);
    } else {
        gemm_kernel<1><<<dim3(C / 128, M / 128), blk, 0, stream>>>(
            aout, wt_proj, b_proj, x, x2, hbuf, alpha, gamma, beta,
            M, C, C, C, C);
    }

    // fc + gelu -> act (reuse qkvbuf region, [M][F])
    gemm_kernel<2><<<dim3(F / 128, M / 128), blk, 0, stream>>>(
        hbuf, wt_fc, b_fc, nullptr, nullptr, qkvbuf, nullptr, nullptr, nullptr,
        M, F, C, C, C);

    // fc2 + residual(x2) -> d_out (f32)
    if (splitK) {
        gemm_kernel<4><<<dim3(C / 128, M / 128, 2), blk, 0, stream>>>(
            qkvbuf, wt_fc2, b_fc2, nullptr, part, nullptr, nullptr, nullptr, nullptr,
            M, C, F / 2, F, F);
        reduce2_kernel<<<dim3(M * C / 1024), blk, 0, stream>>>(part, b_fc2, x2, out, M * C);
    } else {
        gemm_kernel<3><<<dim3(C / 128, M / 128), blk, 0, stream>>>(
            qkvbuf, wt_fc2, b_fc2, x2, out, nullptr, nullptr, nullptr, nullptr,
            M, C, F, F, F);
    }
}

// Round 8
// 252.735 us; speedup vs baseline: 2.5040x; 1.0800x over previous
//
#include <hip/hip_runtime.h>
#include <cstdint>
#include <cstddef>

typedef __bf16 bf16;
typedef __bf16 bf16x8 __attribute__((ext_vector_type(8)));
typedef __bf16 bf16x4 __attribute__((ext_vector_type(4)));
typedef float f32x4 __attribute__((ext_vector_type(4)));

#define DEVI __device__ __forceinline__

DEVI void gload_lds16(const bf16* g, bf16* l) {
    __builtin_amdgcn_global_load_lds(
        (const __attribute__((address_space(1))) void*)(const void*)g,
        (__attribute__((address_space(3))) void*)(void*)l, 16, 0, 0);
}

// ---------------- weight convert + transpose: W[K][N] f32 -> Wt[N][K] bf16 ----
__global__ void conv_t_kernel(const float* __restrict__ W, bf16* __restrict__ Wt,
                              int K, int N) {
    __shared__ float tile[64][65];
    const int tid = threadIdx.x;
    const int c  = tid & 63;
    const int r4 = tid >> 6;   // 0..3
    const int n0 = blockIdx.x * 64;
    const int k0 = blockIdx.y * 64;
#pragma unroll
    for (int r = 0; r < 64; r += 4)
        tile[r + r4][c] = W[(size_t)(k0 + r + r4) * N + n0 + c];
    __syncthreads();
#pragma unroll
    for (int r = 0; r < 64; r += 4)
        Wt[(size_t)(n0 + r + r4) * K + k0 + c] = (bf16)tile[c][r + r4];
}

// ---------------- DyT: h = gamma*tanh(alpha*x)+beta  (f32 -> bf16) -----------
__global__ void dyt_kernel(const float* __restrict__ x, const float* __restrict__ alpha,
                           const float* __restrict__ gamma, const float* __restrict__ beta,
                           bf16* __restrict__ h, int total) {
    int i4 = (blockIdx.x * 256 + threadIdx.x) * 4;
    if (i4 >= total) return;
    float a = alpha[0];
    float4 xv = *(const float4*)&x[i4];
    int c = i4 & 1023;
    float4 g  = *(const float4*)&gamma[c];
    float4 bt = *(const float4*)&beta[c];
    bf16x4 o;
    o[0] = (bf16)(g.x * tanhf(xv.x * a) + bt.x);
    o[1] = (bf16)(g.y * tanhf(xv.y * a) + bt.y);
    o[2] = (bf16)(g.z * tanhf(xv.z * a) + bt.z);
    o[3] = (bf16)(g.w * tanhf(xv.w * a) + bt.w);
    *(bf16x4*)&h[i4] = o;
}

// ---------------- reduce for split-K fc2: out = p0 + p1 + bias + resid -------
__global__ void reduce2_kernel(const float* __restrict__ p, const float* __restrict__ bias,
                               const float* __restrict__ resid, float* __restrict__ out,
                               int total) {
    int i4 = (blockIdx.x * 256 + threadIdx.x) * 4;
    if (i4 >= total) return;
    float4 a = *(const float4*)&p[i4];
    float4 bsec = *(const float4*)&p[(size_t)total + i4];
    float4 r = *(const float4*)&resid[i4];
    int c = i4 & 1023;
    float4 bb = *(const float4*)&bias[c];
    float4 o;
    o.x = a.x + bsec.x + r.x + bb.x;
    o.y = a.y + bsec.y + r.y + bb.y;
    o.z = a.z + bsec.z + r.z + bb.z;
    o.w = a.w + bsec.w + r.w + bb.w;
    *(float4*)&out[i4] = o;
}

// ---- reduce for split-K proj: v = p0+p1+bias+resid; xout=v; hout=DyT(v) -----
__global__ void reduce2_dyt_kernel(const float* __restrict__ p, const float* __restrict__ bias,
                                   const float* __restrict__ resid,
                                   float* __restrict__ xout, bf16* __restrict__ hout,
                                   const float* __restrict__ alpha,
                                   const float* __restrict__ gamma,
                                   const float* __restrict__ beta, int total) {
    int i4 = (blockIdx.x * 256 + threadIdx.x) * 4;
    if (i4 >= total) return;
    float a = alpha[0];
    float4 p0 = *(const float4*)&p[i4];
    float4 p1 = *(const float4*)&p[(size_t)total + i4];
    float4 r  = *(const float4*)&resid[i4];
    int c = i4 & 1023;
    float4 bb = *(const float4*)&bias[c];
    float4 g  = *(const float4*)&gamma[c];
    float4 bt = *(const float4*)&beta[c];
    float4 v;
    v.x = p0.x + p1.x + r.x + bb.x;
    v.y = p0.y + p1.y + r.y + bb.y;
    v.z = p0.z + p1.z + r.z + bb.z;
    v.w = p0.w + p1.w + r.w + bb.w;
    *(float4*)&xout[i4] = v;
    bf16x4 o;
    o[0] = (bf16)(g.x * tanhf(v.x * a) + bt.x);
    o[1] = (bf16)(g.y * tanhf(v.y * a) + bt.y);
    o[2] = (bf16)(g.z * tanhf(v.z * a) + bt.z);
    o[3] = (bf16)(g.w * tanhf(v.w * a) + bt.w);
    *(bf16x4*)&hout[i4] = o;
}

// ---------------- GEMM: C = A[M][lda] @ Wt[N][ldb]^T, 128x128x32, 4 waves ----
// 2-phase prefetch; LDS group-swizzled both-sides; bijective XCD swizzle.
// OP 0: out_bf16 = (acc + bias) * (col<1024 ? 0.125*log2e : 1)   (QKV, Q pre-scaled)
// OP 1: v = acc+bias+resid; out_f32 = v; out_bf16 = DyT(v)
// OP 2: out_bf16 = gelu_exact(acc + bias)             (fc)
// OP 3: out_f32 = acc + bias + resid                  (full-K + resid)
// OP 4: out_f32[z*M*N + idx] = acc                    (split-K partial)
template<int OP>
__global__ void gemm_kernel(const bf16* __restrict__ A, const bf16* __restrict__ Wt,
                            const float* __restrict__ bias, const float* resid,
                            float* outf, bf16* outb,
                            const float* __restrict__ alpha_p,
                            const float* __restrict__ gamma,
                            const float* __restrict__ beta,
                            int M, int N, int K, int lda, int ldb) {
    __shared__ bf16 As[2][128 * 32];
    __shared__ bf16 Bs[2][128 * 32];
    const int tid  = threadIdx.x;
    const int lane = tid & 63;
    const int w    = tid >> 6;
    const int wr   = w >> 1, wc = w & 1;

    const int nwgx = gridDim.x;
    const int nwg  = gridDim.x * gridDim.y;
    const int orig = blockIdx.y * nwgx + blockIdx.x;
    const int cpx  = nwg >> 3;
    const int swz  = (orig & 7) * cpx + (orig >> 3);
    const int bm = (swz / nwgx) * 128;
    const int bn = (swz % nwgx) * 128;
    const int kz = blockIdx.z * K;          // split-K offset

    f32x4 acc[4][4] = {};

    const int srow = tid >> 2;
    const int sgrp = ((tid & 3) ^ ((srow >> 1) & 3)) * 8;
    const bf16* a0 = A  + (size_t)(bm + srow) * lda + kz + sgrp;
    const bf16* a1 = a0 + (size_t)64 * lda;
    const bf16* b0 = Wt + (size_t)(bn + srow) * ldb + kz + sgrp;
    const bf16* b1 = b0 + (size_t)64 * ldb;

    auto stage = [&](int buf) {
        gload_lds16(a0, &As[buf][tid * 8]);
        gload_lds16(a1, &As[buf][2048 + tid * 8]);
        gload_lds16(b0, &Bs[buf][tid * 8]);
        gload_lds16(b1, &Bs[buf][2048 + tid * 8]);
        a0 += 32; a1 += 32; b0 += 32; b1 += 32;
    };

    const int lh = lane >> 4, lm = lane & 15;
    const int arow = wr * 64 + lm;
    const int brow = wc * 64 + lm;
    const int gsw = (lh ^ ((lm >> 1) & 3)) * 8;   // swizzled group offset

    stage(0);
    __syncthreads();

    const int nk = K >> 5;
    for (int kt = 0; kt < nk; ++kt) {
        const int cur = kt & 1;
        if (kt + 1 < nk) stage(cur ^ 1);
        bf16x8 af[4], bfr[4];
#pragma unroll
        for (int i = 0; i < 4; i++)
            af[i] = *(const bf16x8*)&As[cur][(arow + i * 16) * 32 + gsw];
#pragma unroll
        for (int i = 0; i < 4; i++)
            bfr[i] = *(const bf16x8*)&Bs[cur][(brow + i * 16) * 32 + gsw];
#pragma unroll
        for (int i = 0; i < 4; i++)
#pragma unroll
            for (int j = 0; j < 4; j++)
                acc[i][j] = __builtin_amdgcn_mfma_f32_16x16x32_bf16(af[i], bfr[j], acc[i][j], 0, 0, 0);
        __syncthreads();
    }

#pragma unroll
    for (int i = 0; i < 4; i++) {
        const int row0 = bm + wr * 64 + i * 16 + lh * 4;
#pragma unroll
        for (int jf = 0; jf < 4; jf++) {
            const int col = bn + wc * 64 + jf * 16 + lm;
            const float bval = (OP == 4) ? 0.f : bias[col];
#pragma unroll
            for (int r = 0; r < 4; r++) {
                const int row = row0 + r;
                const size_t idx = (size_t)row * N + col;
                float v = acc[i][jf][r] + bval;
                if (OP == 0) {
                    const float qs = (col < 1024) ? 0.18033688011f : 1.0f; // 0.125*log2(e)
                    outb[idx] = (bf16)(v * qs);
                } else if (OP == 1) {
                    v += resid[idx];
                    outf[idx] = v;
                    float hh = gamma[col] * tanhf(v * alpha_p[0]) + beta[col];
                    outb[idx] = (bf16)hh;
                } else if (OP == 2) {
                    float g = 0.5f * v * (1.0f + erff(v * 0.70710678118f));
                    outb[idx] = (bf16)g;
                } else if (OP == 3) {
                    v += resid[idx];
                    outf[idx] = v;
                } else {
                    outf[(size_t)blockIdx.z * M * N + idx] = v;
                }
            }
        }
    }
}

// ---------------- causal flash attention, H=16 D=64 T=2048 -------------------
// Paired q-tiles (j, 31-j): every block does exactly 33 tile-passes sharing
// one staged K/V (LDS) -> half the blocks, -26% K/V fetch, no causal tail.
// K via dbuf global_load_lds (swizzled); V reg-staged transposed. Swapped
// QK^T and swapped PV -> O^T accumulator, all softmax state in-lane. Q comes
// pre-scaled by 0.125*log2e. Defer-max (THR=8, log2 domain).
__global__ void attn_kernel(const bf16* __restrict__ qkv, bf16* __restrict__ out) {
    const int j  = blockIdx.x;          // pair index 0..15
    const int bh = blockIdx.y;          // b*16 + h
    const int b = bh >> 4, h = bh & 15;
    const int tid = threadIdx.x, lane = tid & 63, w = tid >> 6;
    const int T = 2048;
    const size_t C3 = 3072;
    const bf16* qb = qkv + (size_t)b * T * C3 + h * 64;
    const bf16* kb = qb + 1024;
    const bf16* vb = qb + 2048;

    __shared__ bf16 Ks[2][64][64];      // [buf][kv][d], d-blocks XOR-swizzled by kv&7
    __shared__ bf16 Vt[2][64][72];      // [buf][d][k-swizzled]
    __shared__ bf16 Pl[4][16][72];      // per-wave P [q][k]

    const int tA = j, tB = 31 - j;
    const int qA = tA * 64 + w * 16;
    const int qB = tB * 64 + w * 16;
    const int lm = lane & 15;
    const int lh = lane >> 4;

    bf16x8 qfA0, qfA1, qfB0, qfB1;
    {
        size_t qo = (size_t)(qA + lm) * C3 + lh * 8;
        qfA0 = *(const bf16x8*)&qb[qo];
        qfA1 = *(const bf16x8*)&qb[qo + 32];
        qo = (size_t)(qB + lm) * C3 + lh * 8;
        qfB0 = *(const bf16x8*)&qb[qo];
        qfB1 = *(const bf16x8*)&qb[qo + 32];
    }
    f32x4 accA[4] = {}, accB[4] = {};   // O^T: acc[df][r] = O[q=lm][d=df*16+lh*4+r]
    float mA = -1e30f, lA = 0.f, mB = -1e30f, lB = 0.f;

    const int nt = tB + 1;
    const int sg = tid & 7;             // d-group (8 rows of Vt)
    const int sq = tid >> 3;            // k-quad, valid 0..15 for tid<128
    bf16x8 rv[4];

    const int krow = tid >> 3;
    const int kcb  = tid & 7;
    const int kcbs = (kcb ^ (krow & 7)) * 8;
    auto stageK = [&](int buf, int k0) {
        gload_lds16(&kb[(size_t)(k0 + krow) * C3 + kcbs],      &Ks[buf][0][0]  + tid * 8);
        gload_lds16(&kb[(size_t)(k0 + 32 + krow) * C3 + kcbs], &Ks[buf][32][0] + tid * 8);
    };
    auto loadV = [&](int k0) {
        if (tid < 128) {
#pragma unroll
            for (int i = 0; i < 4; ++i)
                rv[i] = *(const bf16x8*)&vb[(size_t)(k0 + sq * 4 + i) * C3 + sg * 8];
        }
    };
    auto writeV = [&](int buf) {
        if (tid < 128) {
            const int cbase = ((((sq >> 1) ^ sg) & 7) << 3) + ((sq & 1) << 2);
#pragma unroll
            for (int e = 0; e < 8; ++e) {
                bf16x4 wv;
                wv[0] = rv[0][e]; wv[1] = rv[1][e]; wv[2] = rv[2][e]; wv[3] = rv[3][e];
                *(bf16x4*)&Vt[buf][sg * 8 + e][cbase] = wv;
            }
        }
    };

    // one q-tile pass over the staged KV tile (QK^T from Ks, softmax, PV)
    auto pass = [&](const bf16x8& q0, const bf16x8& q1, f32x4 (&acc)[4],
                    float& mS, float& lS, int qg, bool diag, int buf, int k0) {
        f32x4 s[4];
#pragma unroll
        for (int f = 0; f < 4; ++f) {
            const int row = f * 16 + lm;
            const int sw = (row & 7);
            bf16x8 kf0v = *(const bf16x8*)&Ks[buf][row][(lh ^ sw) * 8];
            bf16x8 kf1v = *(const bf16x8*)&Ks[buf][row][((lh + 4) ^ sw) * 8];
            f32x4 z = {};
            z = __builtin_amdgcn_mfma_f32_16x16x32_bf16(kf0v, q0, z, 0, 0, 0);
            z = __builtin_amdgcn_mfma_f32_16x16x32_bf16(kf1v, q1, z, 0, 0, 0);
            s[f] = z;
        }
        if (diag) {
#pragma unroll
            for (int f = 0; f < 4; ++f)
#pragma unroll
                for (int r = 0; r < 4; ++r) {
                    const int kgl = k0 + f * 16 + lh * 4 + r;
                    s[f][r] = (kgl > qg) ? -1e30f : s[f][r];
                }
        }
        // row max via max3 tree + 2 shfl
        float a0 = fmaxf(fmaxf(s[0][0], s[0][1]), s[0][2]);
        float a1 = fmaxf(fmaxf(s[0][3], s[1][0]), s[1][1]);
        float a2 = fmaxf(fmaxf(s[1][2], s[1][3]), s[2][0]);
        float a3 = fmaxf(fmaxf(s[2][1], s[2][2]), s[2][3]);
        float a4 = fmaxf(fmaxf(s[3][0], s[3][1]), s[3][2]);
        float b0 = fmaxf(fmaxf(a0, a1), a2);
        float b1 = fmaxf(fmaxf(a3, a4), s[3][3]);
        float pm = fmaxf(b0, b1);
        pm = fmaxf(pm, __shfl_xor(pm, 16));
        pm = fmaxf(pm, __shfl_xor(pm, 32));
        if (!__all(pm - mS <= 8.f)) {
            const float mnew = fmaxf(mS, pm);
            const float corr = __builtin_amdgcn_exp2f(mS - mnew);
            mS = mnew;
            lS *= corr;
#pragma unroll
            for (int df = 0; df < 4; ++df)
#pragma unroll
                for (int r = 0; r < 4; ++r) acc[df][r] *= corr;
        }
        float rs = 0.f;
#pragma unroll
        for (int f = 0; f < 4; ++f) {
            bf16x4 pw;
#pragma unroll
            for (int r = 0; r < 4; ++r) {
                const float pv = __builtin_amdgcn_exp2f(s[f][r] - mS);
                rs += pv;
                pw[r] = (bf16)pv;
            }
            *(bf16x4*)&Pl[w][lm][f * 16 + lh * 4] = pw;
        }
        rs += __shfl_xor(rs, 16);
        rs += __shfl_xor(rs, 32);
        lS += rs;
#pragma unroll
        for (int kk = 0; kk < 2; ++kk) {
            bf16x8 pa = *(const bf16x8*)&Pl[w][lm][kk * 32 + lh * 8];
            const int kblk = 4 * kk + lh;
#pragma unroll
            for (int df = 0; df < 4; ++df) {
                const int dr = df * 16 + lm;
                bf16x8 vf = *(const bf16x8*)&Vt[buf][dr][((kblk ^ ((dr >> 3) & 7)) << 3)];
                acc[df] = __builtin_amdgcn_mfma_f32_16x16x32_bf16(vf, pa, acc[df], 0, 0, 0);
            }
        }
    };

    stageK(0, 0);
    loadV(0);
    writeV(0);
    __syncthreads();

    for (int kt = 0; kt < nt; ++kt) {
        const int k0 = kt * 64;
        const int buf = kt & 1;
        if (kt + 1 < nt) {
            stageK(buf ^ 1, k0 + 64);
            loadV(k0 + 64);
        }
        if (kt <= tA)
            pass(qfA0, qfA1, accA, mA, lA, qA + lm, kt == tA, buf, k0);
        if (kt + 1 < nt) writeV(buf ^ 1);
        pass(qfB0, qfB1, accB, mB, lB, qB + lm, kt == tB, buf, k0);
        __syncthreads();
    }

    // epilogue: in-lane normalize, per-row bf16x4 stores (both q-tiles)
    bf16* obase = out + (size_t)b * T * 1024 + h * 64;
    {
        const float linv = 1.0f / lA;
        bf16* ob = obase + (size_t)(qA + lm) * 1024;
#pragma unroll
        for (int df = 0; df < 4; ++df) {
            bf16x4 st;
#pragma unroll
            for (int r = 0; r < 4; ++r) st[r] = (bf16)(accA[df][r] * linv);
            *(bf16x4*)&ob[df * 16 + lh * 4] = st;
        }
    }
    {
        const float linv = 1.0f / lB;
        bf16* ob = obase + (size_t)(qB + lm) * 1024;
#pragma unroll
        for (int df = 0; df < 4; ++df) {
            bf16x4 st;
#pragma unroll
            for (int r = 0; r < 4; ++r) st[r] = (bf16)(accB[df][r] * linv);
            *(bf16x4*)&ob[df * 16 + lh * 4] = st;
        }
    }
}

// -----------------------------------------------------------------------------
extern "C" void kernel_launch(void* const* d_in, const int* in_sizes, int n_in,
                              void* d_out, int out_size, void* d_ws, size_t ws_size,
                              hipStream_t stream) {
    const float* x      = (const float*)d_in[0];
    const float* alpha  = (const float*)d_in[1];
    const float* gamma  = (const float*)d_in[2];
    const float* beta   = (const float*)d_in[3];
    const float* w_attn = (const float*)d_in[4];
    const float* b_attn = (const float*)d_in[5];
    const float* w_proj = (const float*)d_in[6];
    const float* b_proj = (const float*)d_in[7];
    const float* w_fc   = (const float*)d_in[8];
    const float* b_fc   = (const float*)d_in[9];
    const float* w_fc2  = (const float*)d_in[10];
    const float* b_fc2  = (const float*)d_in[11];
    float* out = (float*)d_out;

    const int M = 4096, C = 1024, F = 4096;
    char* ws = (char*)d_ws;
    bf16* wt_attn = (bf16*)ws;                        // [3C][C]   6 MB
    bf16* wt_proj = wt_attn + (size_t)3 * C * C;      // [C][C]    2 MB
    bf16* wt_fc   = wt_proj + (size_t)C * C;          // [F][C]    8 MB
    bf16* wt_fc2  = wt_fc   + (size_t)F * C;          // [C][F]    8 MB
    bf16* hbuf    = wt_fc2  + (size_t)C * F;          // [M][C]    8 MB (h, then h2)
    bf16* qkvbuf  = hbuf    + (size_t)M * C;          // [M][3C] then act [M][F] 32 MB
    bf16* aout    = qkvbuf  + (size_t)M * F;          // [M][C]    8 MB
    float* x2     = (float*)(aout + (size_t)M * C);   // [M][C]   16 MB
    float* part   = x2 + (size_t)M * C;               // 2x [M][C] f32, 32 MB
    const size_t need = (size_t)(88 + 32) * 1024 * 1024;
    const bool splitK = ws_size >= need;

    dim3 blk(256);
    conv_t_kernel<<<dim3(3 * C / 64, C / 64), blk, 0, stream>>>(w_attn, wt_attn, C, 3 * C);
    conv_t_kernel<<<dim3(C / 64, C / 64),     blk, 0, stream>>>(w_proj, wt_proj, C, C);
    conv_t_kernel<<<dim3(F / 64, C / 64),     blk, 0, stream>>>(w_fc,   wt_fc,   C, F);
    conv_t_kernel<<<dim3(C / 64, F / 64),     blk, 0, stream>>>(w_fc2,  wt_fc2,  F, C);

    dyt_kernel<<<dim3(M * C / 1024), blk, 0, stream>>>(x, alpha, gamma, beta, hbuf, M * C);

    // QKV: [M][3C] = h @ w_attn  (Q columns pre-scaled by 0.125*log2e)
    gemm_kernel<0><<<dim3(3 * C / 128, M / 128), blk, 0, stream>>>(
        hbuf, wt_attn, b_attn, nullptr, nullptr, qkvbuf, nullptr, nullptr, nullptr,
        M, 3 * C, C, C, C);

    attn_kernel<<<dim3(16, 32), blk, 0, stream>>>(qkvbuf, aout);

    // proj + residual(x) -> x2 (f32) and h2 = DyT(x2) (bf16, into hbuf)
    if (splitK) {
        gemm_kernel<4><<<dim3(C / 128, M / 128, 2), blk, 0, stream>>>(
            aout, wt_proj, b_proj, nullptr, part, nullptr, nullptr, nullptr, nullptr,
            M, C, C / 2, C, C);
        reduce2_dyt_kernel<<<dim3(M * C / 1024), blk, 0, stream>>>(
            part, b_proj, x, x2, hbuf, alpha, gamma, beta, M * C);
    } else {
        gemm_kernel<1><<<dim3(C / 128, M / 128), blk, 0, stream>>>(
            aout, wt_proj, b_proj, x, x2, hbuf, alpha, gamma, beta,
            M, C, C, C, C);
    }

    // fc + gelu -> act (reuse qkvbuf region, [M][F])
    gemm_kernel<2><<<dim3(F / 128, M / 128), blk, 0, stream>>>(
        hbuf, wt_fc, b_fc, nullptr, nullptr, qkvbuf, nullptr, nullptr, nullptr,
        M, F, C, C, C);

    // fc2 + residual(x2) -> d_out (f32)
    if (splitK) {
        gemm_kernel<4><<<dim3(C / 128, M / 128, 2), blk, 0, stream>>>(
            qkvbuf, wt_fc2, b_fc2, nullptr, part, nullptr, nullptr, nullptr, nullptr,
            M, C, F / 2, F, F);
        reduce2_kernel<<<dim3(M * C / 1024), blk, 0, stream>>>(part, b_fc2, x2, out, M * C);
    } else {
        gemm_kernel<3><<<dim3(C / 128, M / 128), blk, 0, stream>>>(
            qkvbuf, wt_fc2, b_fc2, x2, out, nullptr, nullptr, nullptr, nullptr,
            M, C, F, F, F);
    }
}

// Round 9
// 247.678 us; speedup vs baseline: 2.5551x; 1.0204x over previous
//
#include <hip/hip_runtime.h>
#include <cstdint>
#include <cstddef>

typedef __bf16 bf16;
typedef __bf16 bf16x8 __attribute__((ext_vector_type(8)));
typedef __bf16 bf16x4 __attribute__((ext_vector_type(4)));
typedef float f32x4 __attribute__((ext_vector_type(4)));

#define DEVI __device__ __forceinline__

DEVI void gload_lds16(const bf16* g, bf16* l) {
    __builtin_amdgcn_global_load_lds(
        (const __attribute__((address_space(1))) void*)(const void*)g,
        (__attribute__((address_space(3))) void*)(void*)l, 16, 0, 0);
}

// fast tanh via hw exp2/rcp: tanh(y) = 1 - 2/(1+exp2(2*log2e*y)); inf-safe.
DEVI float fast_tanh(float y) {
    float t = __builtin_amdgcn_exp2f(2.88539008f * y);
    return 1.f - 2.f * __builtin_amdgcn_rcpf(1.f + t);
}

// ---------------- weight convert + transpose: W[K][N] f32 -> Wt[N][K] bf16 ----
__global__ void conv_t_kernel(const float* __restrict__ W, bf16* __restrict__ Wt,
                              int K, int N) {
    __shared__ float tile[64][65];
    const int tid = threadIdx.x;
    const int c  = tid & 63;
    const int r4 = tid >> 6;   // 0..3
    const int n0 = blockIdx.x * 64;
    const int k0 = blockIdx.y * 64;
#pragma unroll
    for (int r = 0; r < 64; r += 4)
        tile[r + r4][c] = W[(size_t)(k0 + r + r4) * N + n0 + c];
    __syncthreads();
#pragma unroll
    for (int r = 0; r < 64; r += 4)
        Wt[(size_t)(n0 + r + r4) * K + k0 + c] = (bf16)tile[c][r + r4];
}

// ---------------- DyT: h = gamma*tanh(alpha*x)+beta  (f32 -> bf16) -----------
__global__ void dyt_kernel(const float* __restrict__ x, const float* __restrict__ alpha,
                           const float* __restrict__ gamma, const float* __restrict__ beta,
                           bf16* __restrict__ h, int total) {
    int i4 = (blockIdx.x * 256 + threadIdx.x) * 4;
    if (i4 >= total) return;
    float a = alpha[0];
    float4 xv = *(const float4*)&x[i4];
    int c = i4 & 1023;
    float4 g  = *(const float4*)&gamma[c];
    float4 bt = *(const float4*)&beta[c];
    bf16x4 o;
    o[0] = (bf16)(g.x * fast_tanh(xv.x * a) + bt.x);
    o[1] = (bf16)(g.y * fast_tanh(xv.y * a) + bt.y);
    o[2] = (bf16)(g.z * fast_tanh(xv.z * a) + bt.z);
    o[3] = (bf16)(g.w * fast_tanh(xv.w * a) + bt.w);
    *(bf16x4*)&h[i4] = o;
}

// ---------------- reduce for split-K fc2: out = p0 + p1 + bias + resid -------
__global__ void reduce2_kernel(const float* __restrict__ p, const float* __restrict__ bias,
                               const float* __restrict__ resid, float* __restrict__ out,
                               int total) {
    int i4 = (blockIdx.x * 256 + threadIdx.x) * 4;
    if (i4 >= total) return;
    float4 a = *(const float4*)&p[i4];
    float4 bsec = *(const float4*)&p[(size_t)total + i4];
    float4 r = *(const float4*)&resid[i4];
    int c = i4 & 1023;
    float4 bb = *(const float4*)&bias[c];
    float4 o;
    o.x = a.x + bsec.x + r.x + bb.x;
    o.y = a.y + bsec.y + r.y + bb.y;
    o.z = a.z + bsec.z + r.z + bb.z;
    o.w = a.w + bsec.w + r.w + bb.w;
    *(float4*)&out[i4] = o;
}

// ---- reduce for split-K proj: v = p0+p1+bias+resid; xout=v; hout=DyT(v) -----
__global__ void reduce2_dyt_kernel(const float* __restrict__ p, const float* __restrict__ bias,
                                   const float* __restrict__ resid,
                                   float* __restrict__ xout, bf16* __restrict__ hout,
                                   const float* __restrict__ alpha,
                                   const float* __restrict__ gamma,
                                   const float* __restrict__ beta, int total) {
    int i4 = (blockIdx.x * 256 + threadIdx.x) * 4;
    if (i4 >= total) return;
    float a = alpha[0];
    float4 p0 = *(const float4*)&p[i4];
    float4 p1 = *(const float4*)&p[(size_t)total + i4];
    float4 r  = *(const float4*)&resid[i4];
    int c = i4 & 1023;
    float4 bb = *(const float4*)&bias[c];
    float4 g  = *(const float4*)&gamma[c];
    float4 bt = *(const float4*)&beta[c];
    float4 v;
    v.x = p0.x + p1.x + r.x + bb.x;
    v.y = p0.y + p1.y + r.y + bb.y;
    v.z = p0.z + p1.z + r.z + bb.z;
    v.w = p0.w + p1.w + r.w + bb.w;
    *(float4*)&xout[i4] = v;
    bf16x4 o;
    o[0] = (bf16)(g.x * fast_tanh(v.x * a) + bt.x);
    o[1] = (bf16)(g.y * fast_tanh(v.y * a) + bt.y);
    o[2] = (bf16)(g.z * fast_tanh(v.z * a) + bt.z);
    o[3] = (bf16)(g.w * fast_tanh(v.w * a) + bt.w);
    *(bf16x4*)&hout[i4] = o;
}

// ---------------- GEMM: C = A[M][lda] @ Wt[N][ldb]^T, 128x128x32, 4 waves ----
// 2-phase prefetch; LDS group-swizzled both-sides; bijective XCD swizzle.
// OP 0: out_bf16 = (acc + bias) * (col<1024 ? 0.125*log2e : 1)   (QKV, Q pre-scaled)
// OP 1: v = acc+bias+resid; out_f32 = v; out_bf16 = DyT(v)
// OP 2: out_bf16 = gelu_tanh(acc + bias)              (fc)
// OP 3: out_f32 = acc + bias + resid                  (full-K + resid)
// OP 4: out_f32[z*M*N + idx] = acc                    (split-K partial)
template<int OP>
__global__ void gemm_kernel(const bf16* __restrict__ A, const bf16* __restrict__ Wt,
                            const float* __restrict__ bias, const float* resid,
                            float* outf, bf16* outb,
                            const float* __restrict__ alpha_p,
                            const float* __restrict__ gamma,
                            const float* __restrict__ beta,
                            int M, int N, int K, int lda, int ldb) {
    __shared__ bf16 As[2][128 * 32];
    __shared__ bf16 Bs[2][128 * 32];
    const int tid  = threadIdx.x;
    const int lane = tid & 63;
    const int w    = tid >> 6;
    const int wr   = w >> 1, wc = w & 1;

    const int nwgx = gridDim.x;
    const int nwg  = gridDim.x * gridDim.y;
    const int orig = blockIdx.y * nwgx + blockIdx.x;
    const int cpx  = nwg >> 3;
    const int swz  = (orig & 7) * cpx + (orig >> 3);
    const int bm = (swz / nwgx) * 128;
    const int bn = (swz % nwgx) * 128;
    const int kz = blockIdx.z * K;          // split-K offset

    f32x4 acc[4][4] = {};

    const int srow = tid >> 2;
    const int sgrp = ((tid & 3) ^ ((srow >> 1) & 3)) * 8;
    const bf16* a0 = A  + (size_t)(bm + srow) * lda + kz + sgrp;
    const bf16* a1 = a0 + (size_t)64 * lda;
    const bf16* b0 = Wt + (size_t)(bn + srow) * ldb + kz + sgrp;
    const bf16* b1 = b0 + (size_t)64 * ldb;

    auto stage = [&](int buf) {
        gload_lds16(a0, &As[buf][tid * 8]);
        gload_lds16(a1, &As[buf][2048 + tid * 8]);
        gload_lds16(b0, &Bs[buf][tid * 8]);
        gload_lds16(b1, &Bs[buf][2048 + tid * 8]);
        a0 += 32; a1 += 32; b0 += 32; b1 += 32;
    };

    const int lh = lane >> 4, lm = lane & 15;
    const int arow = wr * 64 + lm;
    const int brow = wc * 64 + lm;
    const int gsw = (lh ^ ((lm >> 1) & 3)) * 8;   // swizzled group offset

    stage(0);
    __syncthreads();

    const int nk = K >> 5;
    for (int kt = 0; kt < nk; ++kt) {
        const int cur = kt & 1;
        if (kt + 1 < nk) stage(cur ^ 1);
        bf16x8 af[4], bfr[4];
#pragma unroll
        for (int i = 0; i < 4; i++)
            af[i] = *(const bf16x8*)&As[cur][(arow + i * 16) * 32 + gsw];
#pragma unroll
        for (int i = 0; i < 4; i++)
            bfr[i] = *(const bf16x8*)&Bs[cur][(brow + i * 16) * 32 + gsw];
#pragma unroll
        for (int i = 0; i < 4; i++)
#pragma unroll
            for (int j = 0; j < 4; j++)
                acc[i][j] = __builtin_amdgcn_mfma_f32_16x16x32_bf16(af[i], bfr[j], acc[i][j], 0, 0, 0);
        __syncthreads();
    }

#pragma unroll
    for (int i = 0; i < 4; i++) {
        const int row0 = bm + wr * 64 + i * 16 + lh * 4;
#pragma unroll
        for (int jf = 0; jf < 4; jf++) {
            const int col = bn + wc * 64 + jf * 16 + lm;
            const float bval = (OP == 4) ? 0.f : bias[col];
#pragma unroll
            for (int r = 0; r < 4; r++) {
                const int row = row0 + r;
                const size_t idx = (size_t)row * N + col;
                float v = acc[i][jf][r] + bval;
                if (OP == 0) {
                    const float qs = (col < 1024) ? 0.18033688011f : 1.0f; // 0.125*log2(e)
                    outb[idx] = (bf16)(v * qs);
                } else if (OP == 1) {
                    v += resid[idx];
                    outf[idx] = v;
                    float hh = gamma[col] * fast_tanh(v * alpha_p[0]) + beta[col];
                    outb[idx] = (bf16)hh;
                } else if (OP == 2) {
                    // tanh-GELU in sigmoid form, inf-safe at both tails
                    float xc = v * (1.f + 0.044715f * v * v);
                    float g = v * __builtin_amdgcn_rcpf(
                        1.f + __builtin_amdgcn_exp2f(-2.30220795f * xc));
                    outb[idx] = (bf16)g;
                } else if (OP == 3) {
                    v += resid[idx];
                    outf[idx] = v;
                } else {
                    outf[(size_t)blockIdx.z * M * N + idx] = v;
                }
            }
        }
    }
}

// ---------------- causal flash attention, H=16 D=64 T=2048 -------------------
// Paired q-tiles (j, 31-j): every block does exactly 33 tile-passes sharing
// one staged K/V (LDS). K via dbuf global_load_lds (swizzled); V reg-staged
// transposed. Swapped QK^T and swapped PV -> O^T accumulator, softmax state
// in-lane. Q pre-scaled by 0.125*log2e. Defer-max (THR=8, log2 domain).
// Vt/Pl row stride 68 (34 dwords -> 2l mod 32 bank step, 2-way = free).
// setprio(1) around MFMA clusters (T5).
__global__ void attn_kernel(const bf16* __restrict__ qkv, bf16* __restrict__ out) {
    const int j  = blockIdx.x;          // pair index 0..15
    const int bh = blockIdx.y;          // b*16 + h
    const int b = bh >> 4, h = bh & 15;
    const int tid = threadIdx.x, lane = tid & 63, w = tid >> 6;
    const int T = 2048;
    const size_t C3 = 3072;
    const bf16* qb = qkv + (size_t)b * T * C3 + h * 64;
    const bf16* kb = qb + 1024;
    const bf16* vb = qb + 2048;

    __shared__ bf16 Ks[2][64][64];      // [buf][kv][d], d-blocks XOR-swizzled by kv&7
    __shared__ bf16 Vt[2][64][68];      // [buf][d][k-swizzled]
    __shared__ bf16 Pl[4][16][68];      // per-wave P [q][k]

    const int tA = j, tB = 31 - j;
    const int qA = tA * 64 + w * 16;
    const int qB = tB * 64 + w * 16;
    const int lm = lane & 15;
    const int lh = lane >> 4;

    bf16x8 qfA0, qfA1, qfB0, qfB1;
    {
        size_t qo = (size_t)(qA + lm) * C3 + lh * 8;
        qfA0 = *(const bf16x8*)&qb[qo];
        qfA1 = *(const bf16x8*)&qb[qo + 32];
        qo = (size_t)(qB + lm) * C3 + lh * 8;
        qfB0 = *(const bf16x8*)&qb[qo];
        qfB1 = *(const bf16x8*)&qb[qo + 32];
    }
    f32x4 accA[4] = {}, accB[4] = {};   // O^T: acc[df][r] = O[q=lm][d=df*16+lh*4+r]
    float mA = -1e30f, lA = 0.f, mB = -1e30f, lB = 0.f;

    const int nt = tB + 1;
    const int sg = tid & 7;             // d-group (8 rows of Vt)
    const int sq = tid >> 3;            // k-quad, valid 0..15 for tid<128
    bf16x8 rv[4];

    const int krow = tid >> 3;
    const int kcb  = tid & 7;
    const int kcbs = (kcb ^ (krow & 7)) * 8;
    auto stageK = [&](int buf, int k0) {
        gload_lds16(&kb[(size_t)(k0 + krow) * C3 + kcbs],      &Ks[buf][0][0]  + tid * 8);
        gload_lds16(&kb[(size_t)(k0 + 32 + krow) * C3 + kcbs], &Ks[buf][32][0] + tid * 8);
    };
    auto loadV = [&](int k0) {
        if (tid < 128) {
#pragma unroll
            for (int i = 0; i < 4; ++i)
                rv[i] = *(const bf16x8*)&vb[(size_t)(k0 + sq * 4 + i) * C3 + sg * 8];
        }
    };
    auto writeV = [&](int buf) {
        if (tid < 128) {
            const int cbase = ((((sq >> 1) ^ sg) & 7) << 3) + ((sq & 1) << 2);
#pragma unroll
            for (int e = 0; e < 8; ++e) {
                bf16x4 wv;
                wv[0] = rv[0][e]; wv[1] = rv[1][e]; wv[2] = rv[2][e]; wv[3] = rv[3][e];
                *(bf16x4*)&Vt[buf][sg * 8 + e][cbase] = wv;
            }
        }
    };

    // one q-tile pass over the staged KV tile (QK^T from Ks, softmax, PV)
    auto pass = [&](const bf16x8& q0, const bf16x8& q1, f32x4 (&acc)[4],
                    float& mS, float& lS, int qg, bool diag, int buf, int k0) {
        f32x4 s[4];
        __builtin_amdgcn_s_setprio(1);
#pragma unroll
        for (int f = 0; f < 4; ++f) {
            const int row = f * 16 + lm;
            const int sw = (row & 7);
            bf16x8 kf0v = *(const bf16x8*)&Ks[buf][row][(lh ^ sw) * 8];
            bf16x8 kf1v = *(const bf16x8*)&Ks[buf][row][((lh + 4) ^ sw) * 8];
            f32x4 z = {};
            z = __builtin_amdgcn_mfma_f32_16x16x32_bf16(kf0v, q0, z, 0, 0, 0);
            z = __builtin_amdgcn_mfma_f32_16x16x32_bf16(kf1v, q1, z, 0, 0, 0);
            s[f] = z;
        }
        __builtin_amdgcn_s_setprio(0);
        if (diag) {
#pragma unroll
            for (int f = 0; f < 4; ++f)
#pragma unroll
                for (int r = 0; r < 4; ++r) {
                    const int kgl = k0 + f * 16 + lh * 4 + r;
                    s[f][r] = (kgl > qg) ? -1e30f : s[f][r];
                }
        }
        // row max via max3 tree + 2 shfl
        float a0 = fmaxf(fmaxf(s[0][0], s[0][1]), s[0][2]);
        float a1 = fmaxf(fmaxf(s[0][3], s[1][0]), s[1][1]);
        float a2 = fmaxf(fmaxf(s[1][2], s[1][3]), s[2][0]);
        float a3 = fmaxf(fmaxf(s[2][1], s[2][2]), s[2][3]);
        float a4 = fmaxf(fmaxf(s[3][0], s[3][1]), s[3][2]);
        float b0 = fmaxf(fmaxf(a0, a1), a2);
        float b1 = fmaxf(fmaxf(a3, a4), s[3][3]);
        float pm = fmaxf(b0, b1);
        pm = fmaxf(pm, __shfl_xor(pm, 16));
        pm = fmaxf(pm, __shfl_xor(pm, 32));
        if (!__all(pm - mS <= 8.f)) {
            const float mnew = fmaxf(mS, pm);
            const float corr = __builtin_amdgcn_exp2f(mS - mnew);
            mS = mnew;
            lS *= corr;
#pragma unroll
            for (int df = 0; df < 4; ++df)
#pragma unroll
                for (int r = 0; r < 4; ++r) acc[df][r] *= corr;
        }
        float rs = 0.f;
#pragma unroll
        for (int f = 0; f < 4; ++f) {
            bf16x4 pw;
#pragma unroll
            for (int r = 0; r < 4; ++r) {
                const float pv = __builtin_amdgcn_exp2f(s[f][r] - mS);
                rs += pv;
                pw[r] = (bf16)pv;
            }
            *(bf16x4*)&Pl[w][lm][f * 16 + lh * 4] = pw;
        }
        rs += __shfl_xor(rs, 16);
        rs += __shfl_xor(rs, 32);
        lS += rs;
        __builtin_amdgcn_s_setprio(1);
#pragma unroll
        for (int kk = 0; kk < 2; ++kk) {
            bf16x8 pa = *(const bf16x8*)&Pl[w][lm][kk * 32 + lh * 8];
            const int kblk = 4 * kk + lh;
#pragma unroll
            for (int df = 0; df < 4; ++df) {
                const int dr = df * 16 + lm;
                bf16x8 vf = *(const bf16x8*)&Vt[buf][dr][((kblk ^ ((dr >> 3) & 7)) << 3)];
                acc[df] = __builtin_amdgcn_mfma_f32_16x16x32_bf16(vf, pa, acc[df], 0, 0, 0);
            }
        }
        __builtin_amdgcn_s_setprio(0);
    };

    stageK(0, 0);
    loadV(0);
    writeV(0);
    __syncthreads();

    for (int kt = 0; kt < nt; ++kt) {
        const int k0 = kt * 64;
        const int buf = kt & 1;
        if (kt + 1 < nt) {
            stageK(buf ^ 1, k0 + 64);
            loadV(k0 + 64);
        }
        if (kt <= tA)
            pass(qfA0, qfA1, accA, mA, lA, qA + lm, kt == tA, buf, k0);
        if (kt + 1 < nt) writeV(buf ^ 1);
        pass(qfB0, qfB1, accB, mB, lB, qB + lm, kt == tB, buf, k0);
        __syncthreads();
    }

    // epilogue: in-lane normalize, per-row bf16x4 stores (both q-tiles)
    bf16* obase = out + (size_t)b * T * 1024 + h * 64;
    {
        const float linv = 1.0f / lA;
        bf16* ob = obase + (size_t)(qA + lm) * 1024;
#pragma unroll
        for (int df = 0; df < 4; ++df) {
            bf16x4 st;
#pragma unroll
            for (int r = 0; r < 4; ++r) st[r] = (bf16)(accA[df][r] * linv);
            *(bf16x4*)&ob[df * 16 + lh * 4] = st;
        }
    }
    {
        const float linv = 1.0f / lB;
        bf16* ob = obase + (size_t)(qB + lm) * 1024;
#pragma unroll
        for (int df = 0; df < 4; ++df) {
            bf16x4 st;
#pragma unroll
            for (int r = 0; r < 4; ++r) st[r] = (bf16)(accB[df][r] * linv);
            *(bf16x4*)&ob[df * 16 + lh * 4] = st;
        }
    }
}

// -----------------------------------------------------------------------------
extern "C" void kernel_launch(void* const* d_in, const int* in_sizes, int n_in,
                              void* d_out, int out_size, void* d_ws, size_t ws_size,
                              hipStream_t stream) {
    const float* x      = (const float*)d_in[0];
    const float* alpha  = (const float*)d_in[1];
    const float* gamma  = (const float*)d_in[2];
    const float* beta   = (const float*)d_in[3];
    const float* w_attn = (const float*)d_in[4];
    const float* b_attn = (const float*)d_in[5];
    const float* w_proj = (const float*)d_in[6];
    const float* b_proj = (const float*)d_in[7];
    const float* w_fc   = (const float*)d_in[8];
    const float* b_fc   = (const float*)d_in[9];
    const float* w_fc2  = (const float*)d_in[10];
    const float* b_fc2  = (const float*)d_in[11];
    float* out = (float*)d_out;

    const int M = 4096, C = 1024, F = 4096;
    char* ws = (char*)d_ws;
    bf16* wt_attn = (bf16*)ws;                        // [3C][C]   6 MB
    bf16* wt_proj = wt_attn + (size_t)3 * C * C;      // [C][C]    2 MB
    bf16* wt_fc   = wt_proj + (size_t)C * C;          // [F][C]    8 MB
    bf16* wt_fc2  = wt_fc   + (size_t)F * C;          // [C][F]    8 MB
    bf16* hbuf    = wt_fc2  + (size_t)C * F;          // [M][C]    8 MB (h, then h2)
    bf16* qkvbuf  = hbuf    + (size_t)M * C;          // [M][3C] then act [M][F] 32 MB
    bf16* aout    = qkvbuf  + (size_t)M * F;          // [M][C]    8 MB
    float* x2     = (float*)(aout + (size_t)M * C);   // [M][C]   16 MB
    float* part   = x2 + (size_t)M * C;               // 2x [M][C] f32, 32 MB
    const size_t need = (size_t)(88 + 32) * 1024 * 1024;
    const bool splitK = ws_size >= need;

    dim3 blk(256);
    conv_t_kernel<<<dim3(3 * C / 64, C / 64), blk, 0, stream>>>(w_attn, wt_attn, C, 3 * C);
    conv_t_kernel<<<dim3(C / 64, C / 64),     blk, 0, stream>>>(w_proj, wt_proj, C, C);
    conv_t_kernel<<<dim3(F / 64, C / 64),     blk, 0, stream>>>(w_fc,   wt_fc,   C, F);
    conv_t_kernel<<<dim3(C / 64, F / 64),     blk, 0, stream>>>(w_fc2,  wt_fc2,  F, C);

    dyt_kernel<<<dim3(M * C / 1024), blk, 0, stream>>>(x, alpha, gamma, beta, hbuf, M * C);

    // QKV: [M][3C] = h @ w_attn  (Q columns pre-scaled by 0.125*log2e)
    gemm_kernel<0><<<dim3(3 * C / 128, M / 128), blk, 0, stream>>>(
        hbuf, wt_attn, b_attn, nullptr, nullptr, qkvbuf, nullptr, nullptr, nullptr,
        M, 3 * C, C, C, C);

    attn_kernel<<<dim3(16, 32), blk, 0, stream>>>(qkvbuf, aout);

    // proj + residual(x) -> x2 (f32) and h2 = DyT(x2) (bf16, into hbuf)
    if (splitK) {
        gemm_kernel<4><<<dim3(C / 128, M / 128, 2), blk, 0, stream>>>(
            aout, wt_proj, b_proj, nullptr, part, nullptr, nullptr, nullptr, nullptr,
            M, C, C / 2, C, C);
        reduce2_dyt_kernel<<<dim3(M * C / 1024), blk, 0, stream>>>(
            part, b_proj, x, x2, hbuf, alpha, gamma, beta, M * C);
    } else {
        gemm_kernel<1><<<dim3(C / 128, M / 128), blk, 0, stream>>>(
            aout, wt_proj, b_proj, x, x2, hbuf, alpha, gamma, beta,
            M, C, C, C, C);
    }

    // fc + gelu -> act (reuse qkvbuf region, [M][F])
    gemm_kernel<2><<<dim3(F / 128, M / 128), blk, 0, stream>>>(
        hbuf, wt_fc, b_fc, nullptr, nullptr, qkvbuf, nullptr, nullptr, nullptr,
        M, F, C, C, C);

    // fc2 + residual(x2) -> d_out (f32)
    if (splitK) {
        gemm_kernel<4><<<dim3(C / 128, M / 128, 2), blk, 0, stream>>>(
            qkvbuf, wt_fc2, b_fc2, nullptr, part, nullptr, nullptr, nullptr, nullptr,
            M, C, F / 2, F, F);
        reduce2_kernel<<<dim3(M * C / 1024), blk, 0, stream>>>(part, b_fc2, x2, out, M * C);
    } else {
        gemm_kernel<3><<<dim3(C / 128, M / 128), blk, 0, stream>>>(
            qkvbuf, wt_fc2, b_fc2, x2, out, nullptr, nullptr, nullptr, nullptr,
            M, C, F, F, F);
    }
}

// Round 10
// 240.671 us; speedup vs baseline: 2.6295x; 1.0291x over previous
//
#include <hip/hip_runtime.h>
#include <cstdint>
#include <cstddef>

typedef __bf16 bf16;
typedef __bf16 bf16x8 __attribute__((ext_vector_type(8)));
typedef __bf16 bf16x4 __attribute__((ext_vector_type(4)));
typedef float f32x4 __attribute__((ext_vector_type(4)));

#define DEVI __device__ __forceinline__

DEVI void gload_lds16(const bf16* g, bf16* l) {
    __builtin_amdgcn_global_load_lds(
        (const __attribute__((address_space(1))) void*)(const void*)g,
        (__attribute__((address_space(3))) void*)(void*)l, 16, 0, 0);
}

// fast tanh via hw exp2/rcp: tanh(y) = 1 - 2/(1+exp2(2*log2e*y)); inf-safe.
DEVI float fast_tanh(float y) {
    float t = __builtin_amdgcn_exp2f(2.88539008f * y);
    return 1.f - 2.f * __builtin_amdgcn_rcpf(1.f + t);
}

// ---------------- weight convert + transpose: W[K][N] f32 -> Wt[N][K] bf16 ----
__global__ void conv_t_kernel(const float* __restrict__ W, bf16* __restrict__ Wt,
                              int K, int N) {
    __shared__ float tile[64][65];
    const int tid = threadIdx.x;
    const int c  = tid & 63;
    const int r4 = tid >> 6;   // 0..3
    const int n0 = blockIdx.x * 64;
    const int k0 = blockIdx.y * 64;
#pragma unroll
    for (int r = 0; r < 64; r += 4)
        tile[r + r4][c] = W[(size_t)(k0 + r + r4) * N + n0 + c];
    __syncthreads();
#pragma unroll
    for (int r = 0; r < 64; r += 4)
        Wt[(size_t)(n0 + r + r4) * K + k0 + c] = (bf16)tile[c][r + r4];
}

// ---------------- DyT: h = gamma*tanh(alpha*x)+beta  (f32 -> bf16) -----------
__global__ void dyt_kernel(const float* __restrict__ x, const float* __restrict__ alpha,
                           const float* __restrict__ gamma, const float* __restrict__ beta,
                           bf16* __restrict__ h, int total) {
    int i4 = (blockIdx.x * 256 + threadIdx.x) * 4;
    if (i4 >= total) return;
    float a = alpha[0];
    float4 xv = *(const float4*)&x[i4];
    int c = i4 & 1023;
    float4 g  = *(const float4*)&gamma[c];
    float4 bt = *(const float4*)&beta[c];
    bf16x4 o;
    o[0] = (bf16)(g.x * fast_tanh(xv.x * a) + bt.x);
    o[1] = (bf16)(g.y * fast_tanh(xv.y * a) + bt.y);
    o[2] = (bf16)(g.z * fast_tanh(xv.z * a) + bt.z);
    o[3] = (bf16)(g.w * fast_tanh(xv.w * a) + bt.w);
    *(bf16x4*)&h[i4] = o;
}

// ---------------- reduce for split-K fc2: out = p0 + p1 + bias + resid -------
__global__ void reduce2_kernel(const float* __restrict__ p, const float* __restrict__ bias,
                               const float* __restrict__ resid, float* __restrict__ out,
                               int total) {
    int i4 = (blockIdx.x * 256 + threadIdx.x) * 4;
    if (i4 >= total) return;
    float4 a = *(const float4*)&p[i4];
    float4 bsec = *(const float4*)&p[(size_t)total + i4];
    float4 r = *(const float4*)&resid[i4];
    int c = i4 & 1023;
    float4 bb = *(const float4*)&bias[c];
    float4 o;
    o.x = a.x + bsec.x + r.x + bb.x;
    o.y = a.y + bsec.y + r.y + bb.y;
    o.z = a.z + bsec.z + r.z + bb.z;
    o.w = a.w + bsec.w + r.w + bb.w;
    *(float4*)&out[i4] = o;
}

// ---- reduce for split-K proj: v = p0+p1+bias+resid; xout=v; hout=DyT(v) -----
__global__ void reduce2_dyt_kernel(const float* __restrict__ p, const float* __restrict__ bias,
                                   const float* __restrict__ resid,
                                   float* __restrict__ xout, bf16* __restrict__ hout,
                                   const float* __restrict__ alpha,
                                   const float* __restrict__ gamma,
                                   const float* __restrict__ beta, int total) {
    int i4 = (blockIdx.x * 256 + threadIdx.x) * 4;
    if (i4 >= total) return;
    float a = alpha[0];
    float4 p0 = *(const float4*)&p[i4];
    float4 p1 = *(const float4*)&p[(size_t)total + i4];
    float4 r  = *(const float4*)&resid[i4];
    int c = i4 & 1023;
    float4 bb = *(const float4*)&bias[c];
    float4 g  = *(const float4*)&gamma[c];
    float4 bt = *(const float4*)&beta[c];
    float4 v;
    v.x = p0.x + p1.x + r.x + bb.x;
    v.y = p0.y + p1.y + r.y + bb.y;
    v.z = p0.z + p1.z + r.z + bb.z;
    v.w = p0.w + p1.w + r.w + bb.w;
    *(float4*)&xout[i4] = v;
    bf16x4 o;
    o[0] = (bf16)(g.x * fast_tanh(v.x * a) + bt.x);
    o[1] = (bf16)(g.y * fast_tanh(v.y * a) + bt.y);
    o[2] = (bf16)(g.z * fast_tanh(v.z * a) + bt.z);
    o[3] = (bf16)(g.w * fast_tanh(v.w * a) + bt.w);
    *(bf16x4*)&hout[i4] = o;
}

// ---------------- GEMM: C = A[M][lda] @ Wt[N][ldb]^T, 128x128x32, 4 waves ----
// 2-phase prefetch; LDS group-swizzled both-sides; bijective XCD swizzle.
// OP 0: out_bf16 = (acc + bias) * (col<1024 ? 0.125*log2e : 1)   (QKV, Q pre-scaled)
// OP 1: v = acc+bias+resid; out_f32 = v; out_bf16 = DyT(v)
// OP 2: out_bf16 = gelu_tanh(acc + bias)              (fc)
// OP 3: out_f32 = acc + bias + resid                  (full-K + resid)
// OP 4: out_f32[z*M*N + idx] = acc                    (split-K partial)
template<int OP>
__global__ void gemm_kernel(const bf16* __restrict__ A, const bf16* __restrict__ Wt,
                            const float* __restrict__ bias, const float* resid,
                            float* outf, bf16* outb,
                            const float* __restrict__ alpha_p,
                            const float* __restrict__ gamma,
                            const float* __restrict__ beta,
                            int M, int N, int K, int lda, int ldb) {
    __shared__ bf16 As[2][128 * 32];
    __shared__ bf16 Bs[2][128 * 32];
    const int tid  = threadIdx.x;
    const int lane = tid & 63;
    const int w    = tid >> 6;
    const int wr   = w >> 1, wc = w & 1;

    const int nwgx = gridDim.x;
    const int nwg  = gridDim.x * gridDim.y;
    const int orig = blockIdx.y * nwgx + blockIdx.x;
    const int cpx  = nwg >> 3;
    const int swz  = (orig & 7) * cpx + (orig >> 3);
    const int bm = (swz / nwgx) * 128;
    const int bn = (swz % nwgx) * 128;
    const int kz = blockIdx.z * K;          // split-K offset

    f32x4 acc[4][4] = {};

    const int srow = tid >> 2;
    const int sgrp = ((tid & 3) ^ ((srow >> 1) & 3)) * 8;
    const bf16* a0 = A  + (size_t)(bm + srow) * lda + kz + sgrp;
    const bf16* a1 = a0 + (size_t)64 * lda;
    const bf16* b0 = Wt + (size_t)(bn + srow) * ldb + kz + sgrp;
    const bf16* b1 = b0 + (size_t)64 * ldb;

    auto stage = [&](int buf) {
        gload_lds16(a0, &As[buf][tid * 8]);
        gload_lds16(a1, &As[buf][2048 + tid * 8]);
        gload_lds16(b0, &Bs[buf][tid * 8]);
        gload_lds16(b1, &Bs[buf][2048 + tid * 8]);
        a0 += 32; a1 += 32; b0 += 32; b1 += 32;
    };

    const int lh = lane >> 4, lm = lane & 15;
    const int arow = wr * 64 + lm;
    const int brow = wc * 64 + lm;
    const int gsw = (lh ^ ((lm >> 1) & 3)) * 8;   // swizzled group offset

    stage(0);
    __syncthreads();

    const int nk = K >> 5;
    for (int kt = 0; kt < nk; ++kt) {
        const int cur = kt & 1;
        if (kt + 1 < nk) stage(cur ^ 1);
        bf16x8 af[4], bfr[4];
#pragma unroll
        for (int i = 0; i < 4; i++)
            af[i] = *(const bf16x8*)&As[cur][(arow + i * 16) * 32 + gsw];
#pragma unroll
        for (int i = 0; i < 4; i++)
            bfr[i] = *(const bf16x8*)&Bs[cur][(brow + i * 16) * 32 + gsw];
#pragma unroll
        for (int i = 0; i < 4; i++)
#pragma unroll
            for (int j = 0; j < 4; j++)
                acc[i][j] = __builtin_amdgcn_mfma_f32_16x16x32_bf16(af[i], bfr[j], acc[i][j], 0, 0, 0);
        __syncthreads();
    }

#pragma unroll
    for (int i = 0; i < 4; i++) {
        const int row0 = bm + wr * 64 + i * 16 + lh * 4;
#pragma unroll
        for (int jf = 0; jf < 4; jf++) {
            const int col = bn + wc * 64 + jf * 16 + lm;
            const float bval = (OP == 4) ? 0.f : bias[col];
#pragma unroll
            for (int r = 0; r < 4; r++) {
                const int row = row0 + r;
                const size_t idx = (size_t)row * N + col;
                float v = acc[i][jf][r] + bval;
                if (OP == 0) {
                    const float qs = (col < 1024) ? 0.18033688011f : 1.0f; // 0.125*log2(e)
                    outb[idx] = (bf16)(v * qs);
                } else if (OP == 1) {
                    v += resid[idx];
                    outf[idx] = v;
                    float hh = gamma[col] * fast_tanh(v * alpha_p[0]) + beta[col];
                    outb[idx] = (bf16)hh;
                } else if (OP == 2) {
                    // tanh-GELU in sigmoid form, inf-safe at both tails
                    float xc = v * (1.f + 0.044715f * v * v);
                    float g = v * __builtin_amdgcn_rcpf(
                        1.f + __builtin_amdgcn_exp2f(-2.30220795f * xc));
                    outb[idx] = (bf16)g;
                } else if (OP == 3) {
                    v += resid[idx];
                    outf[idx] = v;
                } else {
                    outf[(size_t)blockIdx.z * M * N + idx] = v;
                }
            }
        }
    }
}

// ---------------- causal flash attention, H=16 D=64 T=2048 -------------------
// Paired q-tiles (j, 31-j); K/V fragments hoisted to REGISTERS once per tile
// and shared by both passes (grid-limited occupancy -> VGPRs are free).
// Both QK^T's issued back-to-back so QK^T_B overlaps softmax_A, PV_A overlaps
// softmax_B. Two Pl slots decouple the passes' LDS traffic. Swapped QK^T and
// swapped PV -> O^T accumulator, softmax state in-lane. Q pre-scaled by
// 0.125*log2e. Defer-max (THR=8, log2 domain).
__global__ void __launch_bounds__(256, 2)
attn_kernel(const bf16* __restrict__ qkv, bf16* __restrict__ out) {
    const int j  = blockIdx.x;          // pair index 0..15
    const int bh = blockIdx.y;          // b*16 + h
    const int b = bh >> 4, h = bh & 15;
    const int tid = threadIdx.x, lane = tid & 63, w = tid >> 6;
    const int T = 2048;
    const size_t C3 = 3072;
    const bf16* qb = qkv + (size_t)b * T * C3 + h * 64;
    const bf16* kb = qb + 1024;
    const bf16* vb = qb + 2048;

    __shared__ bf16 Ks[2][64][64];      // [buf][kv][d], d-blocks XOR-swizzled by kv&7
    __shared__ bf16 Vt[2][64][72];      // [buf][d][k-swizzled]
    __shared__ bf16 Pl[2][4][16][72];   // [slot][wave][q][k]

    const int tA = j, tB = 31 - j;
    const int qA = tA * 64 + w * 16;
    const int qB = tB * 64 + w * 16;
    const int lm = lane & 15;
    const int lh = lane >> 4;

    bf16x8 qfA0, qfA1, qfB0, qfB1;
    {
        size_t qo = (size_t)(qA + lm) * C3 + lh * 8;
        qfA0 = *(const bf16x8*)&qb[qo];
        qfA1 = *(const bf16x8*)&qb[qo + 32];
        qo = (size_t)(qB + lm) * C3 + lh * 8;
        qfB0 = *(const bf16x8*)&qb[qo];
        qfB1 = *(const bf16x8*)&qb[qo + 32];
    }
    f32x4 accA[4] = {}, accB[4] = {};   // O^T: acc[df][r] = O[q=lm][d=df*16+lh*4+r]
    float mA = -1e30f, lA = 0.f, mB = -1e30f, lB = 0.f;

    const int nt = tB + 1;
    const int sg = tid & 7;             // d-group (8 rows of Vt)
    const int sq = tid >> 3;            // k-quad, valid 0..15 for tid<128
    bf16x8 rv[4];

    const int krow = tid >> 3;
    const int kcb  = tid & 7;
    const int kcbs = (kcb ^ (krow & 7)) * 8;
    auto stageK = [&](int buf, int k0) {
        gload_lds16(&kb[(size_t)(k0 + krow) * C3 + kcbs],      &Ks[buf][0][0]  + tid * 8);
        gload_lds16(&kb[(size_t)(k0 + 32 + krow) * C3 + kcbs], &Ks[buf][32][0] + tid * 8);
    };
    auto loadV = [&](int k0) {
        if (tid < 128) {
#pragma unroll
            for (int i = 0; i < 4; ++i)
                rv[i] = *(const bf16x8*)&vb[(size_t)(k0 + sq * 4 + i) * C3 + sg * 8];
        }
    };
    auto writeV = [&](int buf) {
        if (tid < 128) {
            const int cbase = ((((sq >> 1) ^ sg) & 7) << 3) + ((sq & 1) << 2);
#pragma unroll
            for (int e = 0; e < 8; ++e) {
                bf16x4 wv;
                wv[0] = rv[0][e]; wv[1] = rv[1][e]; wv[2] = rv[2][e]; wv[3] = rv[3][e];
                *(bf16x4*)&Vt[buf][sg * 8 + e][cbase] = wv;
            }
        }
    };

    // softmax + PV for one pass; kf/vf shared registers
    auto softmax_pv = [&](f32x4 (&s)[4], f32x4 (&acc)[4], float& mS, float& lS,
                          int qg, bool diag, int k0, int slot, bf16x8 (&vf)[2][4]) {
        if (diag) {
#pragma unroll
            for (int f = 0; f < 4; ++f)
#pragma unroll
                for (int r = 0; r < 4; ++r) {
                    const int kgl = k0 + f * 16 + lh * 4 + r;
                    s[f][r] = (kgl > qg) ? -1e30f : s[f][r];
                }
        }
        float a0 = fmaxf(fmaxf(s[0][0], s[0][1]), s[0][2]);
        float a1 = fmaxf(fmaxf(s[0][3], s[1][0]), s[1][1]);
        float a2 = fmaxf(fmaxf(s[1][2], s[1][3]), s[2][0]);
        float a3 = fmaxf(fmaxf(s[2][1], s[2][2]), s[2][3]);
        float a4 = fmaxf(fmaxf(s[3][0], s[3][1]), s[3][2]);
        float b0 = fmaxf(fmaxf(a0, a1), a2);
        float b1 = fmaxf(fmaxf(a3, a4), s[3][3]);
        float pm = fmaxf(b0, b1);
        pm = fmaxf(pm, __shfl_xor(pm, 16));
        pm = fmaxf(pm, __shfl_xor(pm, 32));
        if (!__all(pm - mS <= 8.f)) {
            const float mnew = fmaxf(mS, pm);
            const float corr = __builtin_amdgcn_exp2f(mS - mnew);
            mS = mnew;
            lS *= corr;
#pragma unroll
            for (int df = 0; df < 4; ++df)
#pragma unroll
                for (int r = 0; r < 4; ++r) acc[df][r] *= corr;
        }
        float rs = 0.f;
#pragma unroll
        for (int f = 0; f < 4; ++f) {
            bf16x4 pw;
#pragma unroll
            for (int r = 0; r < 4; ++r) {
                const float pv = __builtin_amdgcn_exp2f(s[f][r] - mS);
                rs += pv;
                pw[r] = (bf16)pv;
            }
            *(bf16x4*)&Pl[slot][w][lm][f * 16 + lh * 4] = pw;
        }
        rs += __shfl_xor(rs, 16);
        rs += __shfl_xor(rs, 32);
        lS += rs;
        __builtin_amdgcn_s_setprio(1);
#pragma unroll
        for (int kk = 0; kk < 2; ++kk) {
            bf16x8 pa = *(const bf16x8*)&Pl[slot][w][lm][kk * 32 + lh * 8];
#pragma unroll
            for (int df = 0; df < 4; ++df)
                acc[df] = __builtin_amdgcn_mfma_f32_16x16x32_bf16(vf[kk][df], pa, acc[df], 0, 0, 0);
        }
        __builtin_amdgcn_s_setprio(0);
    };

    stageK(0, 0);
    loadV(0);
    writeV(0);
    __syncthreads();

    for (int kt = 0; kt < nt; ++kt) {
        const int k0 = kt * 64;
        const int buf = kt & 1;
        const bool hasNext = (kt + 1 < nt);
        if (hasNext) {
            stageK(buf ^ 1, k0 + 64);
            loadV(k0 + 64);
        }

        // hoist K and V fragments to registers (shared by both passes)
        bf16x8 kf[4][2];
#pragma unroll
        for (int f = 0; f < 4; ++f) {
            const int row = f * 16 + lm;
            const int sw = (row & 7);
            kf[f][0] = *(const bf16x8*)&Ks[buf][row][(lh ^ sw) * 8];
            kf[f][1] = *(const bf16x8*)&Ks[buf][row][((lh + 4) ^ sw) * 8];
        }
        bf16x8 vf[2][4];
#pragma unroll
        for (int kk = 0; kk < 2; ++kk)
#pragma unroll
            for (int df = 0; df < 4; ++df) {
                const int dr = df * 16 + lm;
                vf[kk][df] = *(const bf16x8*)&Vt[buf][dr][(((4 * kk + lh) ^ ((dr >> 3) & 7)) << 3)];
            }

        const bool actA = (kt <= tA);
        f32x4 sA[4], sB[4];
        __builtin_amdgcn_s_setprio(1);
#pragma unroll
        for (int f = 0; f < 4; ++f) {
            f32x4 z = {};
            z = __builtin_amdgcn_mfma_f32_16x16x32_bf16(kf[f][0], qfB0, z, 0, 0, 0);
            z = __builtin_amdgcn_mfma_f32_16x16x32_bf16(kf[f][1], qfB1, z, 0, 0, 0);
            sB[f] = z;
        }
        if (actA) {
#pragma unroll
            for (int f = 0; f < 4; ++f) {
                f32x4 z = {};
                z = __builtin_amdgcn_mfma_f32_16x16x32_bf16(kf[f][0], qfA0, z, 0, 0, 0);
                z = __builtin_amdgcn_mfma_f32_16x16x32_bf16(kf[f][1], qfA1, z, 0, 0, 0);
                sA[f] = z;
            }
        }
        __builtin_amdgcn_s_setprio(0);

        if (actA)
            softmax_pv(sA, accA, mA, lA, qA + lm, kt == tA, k0, 0, vf);
        if (hasNext) writeV(buf ^ 1);
        softmax_pv(sB, accB, mB, lB, qB + lm, kt == tB, k0, 1, vf);
        __syncthreads();
    }

    // epilogue: in-lane normalize, per-row bf16x4 stores (both q-tiles)
    bf16* obase = out + (size_t)b * T * 1024 + h * 64;
    {
        const float linv = 1.0f / lA;
        bf16* ob = obase + (size_t)(qA + lm) * 1024;
#pragma unroll
        for (int df = 0; df < 4; ++df) {
            bf16x4 st;
#pragma unroll
            for (int r = 0; r < 4; ++r) st[r] = (bf16)(accA[df][r] * linv);
            *(bf16x4*)&ob[df * 16 + lh * 4] = st;
        }
    }
    {
        const float linv = 1.0f / lB;
        bf16* ob = obase + (size_t)(qB + lm) * 1024;
#pragma unroll
        for (int df = 0; df < 4; ++df) {
            bf16x4 st;
#pragma unroll
            for (int r = 0; r < 4; ++r) st[r] = (bf16)(accB[df][r] * linv);
            *(bf16x4*)&ob[df * 16 + lh * 4] = st;
        }
    }
}

// -----------------------------------------------------------------------------
extern "C" void kernel_launch(void* const* d_in, const int* in_sizes, int n_in,
                              void* d_out, int out_size, void* d_ws, size_t ws_size,
                              hipStream_t stream) {
    const float* x      = (const float*)d_in[0];
    const float* alpha  = (const float*)d_in[1];
    const float* gamma  = (const float*)d_in[2];
    const float* beta   = (const float*)d_in[3];
    const float* w_attn = (const float*)d_in[4];
    const float* b_attn = (const float*)d_in[5];
    const float* w_proj = (const float*)d_in[6];
    const float* b_proj = (const float*)d_in[7];
    const float* w_fc   = (const float*)d_in[8];
    const float* b_fc   = (const float*)d_in[9];
    const float* w_fc2  = (const float*)d_in[10];
    const float* b_fc2  = (const float*)d_in[11];
    float* out = (float*)d_out;

    const int M = 4096, C = 1024, F = 4096;
    char* ws = (char*)d_ws;
    bf16* wt_attn = (bf16*)ws;                        // [3C][C]   6 MB
    bf16* wt_proj = wt_attn + (size_t)3 * C * C;      // [C][C]    2 MB
    bf16* wt_fc   = wt_proj + (size_t)C * C;          // [F][C]    8 MB
    bf16* wt_fc2  = wt_fc   + (size_t)F * C;          // [C][F]    8 MB
    bf16* hbuf    = wt_fc2  + (size_t)C * F;          // [M][C]    8 MB (h, then h2)
    bf16* qkvbuf  = hbuf    + (size_t)M * C;          // [M][3C] then act [M][F] 32 MB
    bf16* aout    = qkvbuf  + (size_t)M * F;          // [M][C]    8 MB
    float* x2     = (float*)(aout + (size_t)M * C);   // [M][C]   16 MB
    float* part   = x2 + (size_t)M * C;               // 2x [M][C] f32, 32 MB
    const size_t need = (size_t)(88 + 32) * 1024 * 1024;
    const bool splitK = ws_size >= need;

    dim3 blk(256);
    conv_t_kernel<<<dim3(3 * C / 64, C / 64), blk, 0, stream>>>(w_attn, wt_attn, C, 3 * C);
    conv_t_kernel<<<dim3(C / 64, C / 64),     blk, 0, stream>>>(w_proj, wt_proj, C, C);
    conv_t_kernel<<<dim3(F / 64, C / 64),     blk, 0, stream>>>(w_fc,   wt_fc,   C, F);
    conv_t_kernel<<<dim3(C / 64, F / 64),     blk, 0, stream>>>(w_fc2,  wt_fc2,  F, C);

    dyt_kernel<<<dim3(M * C / 1024), blk, 0, stream>>>(x, alpha, gamma, beta, hbuf, M * C);

    // QKV: [M][3C] = h @ w_attn  (Q columns pre-scaled by 0.125*log2e)
    gemm_kernel<0><<<dim3(3 * C / 128, M / 128), blk, 0, stream>>>(
        hbuf, wt_attn, b_attn, nullptr, nullptr, qkvbuf, nullptr, nullptr, nullptr,
        M, 3 * C, C, C, C);

    attn_kernel<<<dim3(16, 32), blk, 0, stream>>>(qkvbuf, aout);

    // proj + residual(x) -> x2 (f32) and h2 = DyT(x2) (bf16, into hbuf)
    if (splitK) {
        gemm_kernel<4><<<dim3(C / 128, M / 128, 2), blk, 0, stream>>>(
            aout, wt_proj, b_proj, nullptr, part, nullptr, nullptr, nullptr, nullptr,
            M, C, C / 2, C, C);
        reduce2_dyt_kernel<<<dim3(M * C / 1024), blk, 0, stream>>>(
            part, b_proj, x, x2, hbuf, alpha, gamma, beta, M * C);
    } else {
        gemm_kernel<1><<<dim3(C / 128, M / 128), blk, 0, stream>>>(
            aout, wt_proj, b_proj, x, x2, hbuf, alpha, gamma, beta,
            M, C, C, C, C);
    }

    // fc + gelu -> act (reuse qkvbuf region, [M][F])
    gemm_kernel<2><<<dim3(F / 128, M / 128), blk, 0, stream>>>(
        hbuf, wt_fc, b_fc, nullptr, nullptr, qkvbuf, nullptr, nullptr, nullptr,
        M, F, C, C, C);

    // fc2 + residual(x2) -> d_out (f32)
    if (splitK) {
        gemm_kernel<4><<<dim3(C / 128, M / 128, 2), blk, 0, stream>>>(
            qkvbuf, wt_fc2, b_fc2, nullptr, part, nullptr, nullptr, nullptr, nullptr,
            M, C, F / 2, F, F);
        reduce2_kernel<<<dim3(M * C / 1024), blk, 0, stream>>>(part, b_fc2, x2, out, M * C);
    } else {
        gemm_kernel<3><<<dim3(C / 128, M / 128), blk, 0, stream>>>(
            qkvbuf, wt_fc2, b_fc2, x2, out, nullptr, nullptr, nullptr, nullptr,
            M, C, F, F, F);
    }
}